// Round 1
// baseline (339.449 us; speedup 1.0000x reference)
//
#include <hip/hip_runtime.h>

#define N_HEAD 16

typedef __attribute__((ext_vector_type(8))) __bf16 bf16x8;
typedef __attribute__((ext_vector_type(8))) short  s16x8;
typedef __attribute__((ext_vector_type(4))) float  f32x4;

static __device__ __forceinline__ short f2bf(float f) {
    unsigned u = __builtin_bit_cast(unsigned, f);
    unsigned r = (u + 0x7FFFu + ((u >> 16) & 1u)) >> 16;
    return (short)r;
}

// ---------------------------------------------------------------- GEMM 1: qkv
#define BM 128
#define BN 128
#define BK 32
#define LDK (BK + 8)   // +16B pad, keeps 16B alignment for ds_read_b128

__global__ __launch_bounds__(256) void qkv_gemm(
    const float* __restrict__ X,     // 4096 x 1024
    const float* __restrict__ W,     // 1024 x 3072
    const float* __restrict__ bias,  // 3072
    short* __restrict__ Qo, short* __restrict__ Ko, short* __restrict__ Vo)
{
    __shared__ short As[BM][LDK];
    __shared__ short Bs[BN][LDK];
    const int K = 1024, N = 3072;
    const int row0 = blockIdx.x * BM, col0 = blockIdx.y * BN;
    const int tid = threadIdx.x;
    const int wave = tid >> 6, lane = tid & 63;
    const int wr = (wave >> 1) * 64, wc = (wave & 1) * 64;
    const int arow = lane & 15, ksub = (lane >> 4) * 8;

    f32x4 acc[4][4] = {};

    for (int k0 = 0; k0 < K; k0 += BK) {
        {   // stage A tile (fp32 -> bf16)
            int c = (tid & 7) * 4;
            int r = tid >> 3;
#pragma unroll
            for (int i = 0; i < 4; ++i) {
                int rr = r + i * 32;
                float4 f = *(const float4*)&X[(size_t)(row0 + rr) * K + k0 + c];
                As[rr][c + 0] = f2bf(f.x); As[rr][c + 1] = f2bf(f.y);
                As[rr][c + 2] = f2bf(f.z); As[rr][c + 3] = f2bf(f.w);
            }
        }
        {   // stage B tile transposed: Bs[n][k]
            int c = (tid & 31) * 4;
            int r = tid >> 5;
#pragma unroll
            for (int i = 0; i < 4; ++i) {
                int rr = r + i * 8;
                float4 f = *(const float4*)&W[(size_t)(k0 + rr) * N + col0 + c];
                Bs[c + 0][rr] = f2bf(f.x); Bs[c + 1][rr] = f2bf(f.y);
                Bs[c + 2][rr] = f2bf(f.z); Bs[c + 3][rr] = f2bf(f.w);
            }
        }
        __syncthreads();
        bf16x8 af[4], bfr[4];
#pragma unroll
        for (int i = 0; i < 4; ++i) af[i]  = *(const bf16x8*)&As[wr + i * 16 + arow][ksub];
#pragma unroll
        for (int j = 0; j < 4; ++j) bfr[j] = *(const bf16x8*)&Bs[wc + j * 16 + arow][ksub];
#pragma unroll
        for (int i = 0; i < 4; ++i)
#pragma unroll
            for (int j = 0; j < 4; ++j)
                acc[i][j] = __builtin_amdgcn_mfma_f32_16x16x32_bf16(af[i], bfr[j], acc[i][j], 0, 0, 0);
        __syncthreads();
    }

    const int ccol = lane & 15, crow = (lane >> 4) * 4;
#pragma unroll
    for (int i = 0; i < 4; ++i)
#pragma unroll
        for (int j = 0; j < 4; ++j)
#pragma unroll
            for (int r = 0; r < 4; ++r) {
                int m = row0 + wr + i * 16 + crow + r;
                int n = col0 + wc + j * 16 + ccol;
                float val = acc[i][j][r] + bias[n];
                int which = n >> 10;
                int nc = n & 1023;
                int head = nc >> 6, hd = nc & 63;
                int b = m >> 11, t = m & 2047;
                if (which == 0) val *= 0.125f;   // fold softmax scale into q (exact pow2)
                short* dst = (which == 0) ? Qo : (which == 1) ? Ko : Vo;
                dst[((size_t)(b * N_HEAD + head) * 2048 + t) * 64 + hd] = f2bf(val);
            }
}

// ---------------------------------------------------------- flash attention
#define QBLK 64
#define KBLK 64
#define LDV (KBLK + 8)

__global__ __launch_bounds__(256) void attn_kernel(
    const short* __restrict__ Q, const short* __restrict__ K,
    const short* __restrict__ V, short* __restrict__ Y)
{
    __shared__ short Vs[64][LDV];       // [hd][key]  (transposed V tile)
    __shared__ short Ps[4][16][LDV];    // per-wave P tile [q][key]
    const int bh = blockIdx.x;          // 0..31
    const int q0 = blockIdx.y * QBLK;
    const int b = bh >> 4, h = bh & 15;
    const short* Qh = Q + (size_t)bh * 2048 * 64;
    const short* Kh = K + (size_t)bh * 2048 * 64;
    const short* Vh = V + (size_t)bh * 2048 * 64;
    const int tid = threadIdx.x, wave = tid >> 6, lane = tid & 63;
    const int qrow0 = q0 + wave * 16;
    const int arow = lane & 15, ksub = (lane >> 4) * 8;
    const int ccol = arow, crow = (lane >> 4) * 4;

    bf16x8 qf[2];
#pragma unroll
    for (int c = 0; c < 2; ++c)
        qf[c] = *(const bf16x8*)&Qh[(size_t)(qrow0 + arow) * 64 + c * 32 + ksub];

    f32x4 o[4] = {};
    float mrow[4] = { -1e30f, -1e30f, -1e30f, -1e30f };
    float lrow[4] = {};

    const int kv_end = q0 + QBLK;
    for (int kt = 0; kt < kv_end; kt += KBLK) {
        __syncthreads();
        {   // stage V transposed: Vs[hd][key]
            int hc = (tid & 7) * 8;
            int kr = tid >> 3;           // 0..31
#pragma unroll
            for (int i = 0; i < 2; ++i) {
                int kk = kr + i * 32;
                s16x8 vv = *(const s16x8*)&Vh[(size_t)(kt + kk) * 64 + hc];
#pragma unroll
                for (int e = 0; e < 8; ++e) Vs[hc + e][kk] = vv[e];
            }
        }
        __syncthreads();

        const bool need_mask = (kt + KBLK) > qrow0;
        f32x4 s[4];
#pragma unroll
        for (int kc = 0; kc < 4; ++kc) {
            f32x4 sv = {};
#pragma unroll
            for (int c = 0; c < 2; ++c) {
                bf16x8 kf = *(const bf16x8*)&Kh[(size_t)(kt + kc * 16 + arow) * 64 + c * 32 + ksub];
                sv = __builtin_amdgcn_mfma_f32_16x16x32_bf16(qf[c], kf, sv, 0, 0, 0);
            }
            if (need_mask) {
#pragma unroll
                for (int r = 0; r < 4; ++r) {
                    int key = kt + kc * 16 + ccol;
                    int qq  = qrow0 + crow + r;
                    if (key > qq) sv[r] = -3.0e38f;
                }
            }
            s[kc] = sv;
        }
        // online softmax (per q-row stats live in 16-lane groups)
        float p[4][4];
#pragma unroll
        for (int r = 0; r < 4; ++r) {
            float v0 = fmaxf(fmaxf(s[0][r], s[1][r]), fmaxf(s[2][r], s[3][r]));
#pragma unroll
            for (int msk = 1; msk < 16; msk <<= 1)
                v0 = fmaxf(v0, __shfl_xor(v0, msk));
            float mnew = fmaxf(mrow[r], v0);
            float sc = __expf(mrow[r] - mnew);
            mrow[r] = mnew;
            lrow[r] *= sc;
#pragma unroll
            for (int j = 0; j < 4; ++j) o[j][r] *= sc;
            float ssum = 0.f;
#pragma unroll
            for (int kc = 0; kc < 4; ++kc) {
                float pv = __expf(s[kc][r] - mnew);
                p[kc][r] = pv;
                ssum += pv;
            }
#pragma unroll
            for (int msk = 1; msk < 16; msk <<= 1)
                ssum += __shfl_xor(ssum, msk);
            lrow[r] += ssum;
        }
        // P -> LDS (per-wave region), then PV
#pragma unroll
        for (int kc = 0; kc < 4; ++kc)
#pragma unroll
            for (int r = 0; r < 4; ++r)
                Ps[wave][crow + r][kc * 16 + ccol] = f2bf(p[kc][r]);
        __threadfence_block();   // order same-wave ds_write -> ds_read
#pragma unroll
        for (int c = 0; c < 2; ++c) {
            bf16x8 pa = *(const bf16x8*)&Ps[wave][arow][c * 32 + ksub];
#pragma unroll
            for (int j = 0; j < 4; ++j) {
                bf16x8 vb = *(const bf16x8*)&Vs[j * 16 + arow][c * 32 + ksub];
                o[j] = __builtin_amdgcn_mfma_f32_16x16x32_bf16(pa, vb, o[j], 0, 0, 0);
            }
        }
    }

#pragma unroll
    for (int j = 0; j < 4; ++j)
#pragma unroll
        for (int r = 0; r < 4; ++r) {
            int t = qrow0 + crow + r;
            float val = o[j][r] / lrow[r];
            Y[((size_t)(b * 2048 + t)) * 1024 + h * 64 + j * 16 + ccol] = f2bf(val);
        }
}

// ---------------------------------------------------------------- GEMM 2: proj
__global__ __launch_bounds__(256) void proj_gemm(
    const short* __restrict__ Yb,    // 4096 x 1024 bf16
    const float* __restrict__ W,     // 1024 x 1024
    const float* __restrict__ bias,  // 1024
    float* __restrict__ Out)         // 4096 x 1024 fp32
{
    __shared__ short As[BM][LDK];
    __shared__ short Bs[BN][LDK];
    const int K = 1024, N = 1024;
    const int row0 = blockIdx.x * BM, col0 = blockIdx.y * BN;
    const int tid = threadIdx.x;
    const int wave = tid >> 6, lane = tid & 63;
    const int wr = (wave >> 1) * 64, wc = (wave & 1) * 64;
    const int arow = lane & 15, ksub = (lane >> 4) * 8;

    f32x4 acc[4][4] = {};

    for (int k0 = 0; k0 < K; k0 += BK) {
        {   // stage A (already bf16)
            int c = (tid & 3) * 8;
            int r = tid >> 2;            // 0..63
#pragma unroll
            for (int i = 0; i < 2; ++i) {
                int rr = r + i * 64;
                s16x8 vv = *(const s16x8*)&Yb[(size_t)(row0 + rr) * K + k0 + c];
                *(s16x8*)&As[rr][c] = vv;
            }
        }
        {   // stage B transposed (fp32 -> bf16)
            int c = (tid & 31) * 4;
            int r = tid >> 5;
#pragma unroll
            for (int i = 0; i < 4; ++i) {
                int rr = r + i * 8;
                float4 f = *(const float4*)&W[(size_t)(k0 + rr) * N + col0 + c];
                Bs[c + 0][rr] = f2bf(f.x); Bs[c + 1][rr] = f2bf(f.y);
                Bs[c + 2][rr] = f2bf(f.z); Bs[c + 3][rr] = f2bf(f.w);
            }
        }
        __syncthreads();
        bf16x8 af[4], bfr[4];
#pragma unroll
        for (int i = 0; i < 4; ++i) af[i]  = *(const bf16x8*)&As[wr + i * 16 + arow][ksub];
#pragma unroll
        for (int j = 0; j < 4; ++j) bfr[j] = *(const bf16x8*)&Bs[wc + j * 16 + arow][ksub];
#pragma unroll
        for (int i = 0; i < 4; ++i)
#pragma unroll
            for (int j = 0; j < 4; ++j)
                acc[i][j] = __builtin_amdgcn_mfma_f32_16x16x32_bf16(af[i], bfr[j], acc[i][j], 0, 0, 0);
        __syncthreads();
    }

    const int ccol = lane & 15, crow = (lane >> 4) * 4;
#pragma unroll
    for (int i = 0; i < 4; ++i)
#pragma unroll
        for (int j = 0; j < 4; ++j)
#pragma unroll
            for (int r = 0; r < 4; ++r) {
                int m = row0 + wr + i * 16 + crow + r;
                int n = col0 + wc + j * 16 + ccol;
                Out[(size_t)m * N + n] = acc[i][j][r] + bias[n];
            }
}

// ------------------------------------------------------------------- launch
extern "C" void kernel_launch(void* const* d_in, const int* in_sizes, int n_in,
                              void* d_out, int out_size, void* d_ws, size_t ws_size,
                              hipStream_t stream) {
    const float* x      = (const float*)d_in[0];
    const float* W_attn = (const float*)d_in[1];
    const float* b_attn = (const float*)d_in[2];
    const float* W_proj = (const float*)d_in[3];
    const float* b_proj = (const float*)d_in[4];
    float* out = (float*)d_out;

    // workspace layout (bf16 = short), 4 buffers of 2*16*2048*64 = 4,194,304 elems
    short* qb = (short*)d_ws;
    short* kb = qb + 4194304;
    short* vb = kb + 4194304;
    short* yb = vb + 4194304;   // (B,T,C) = 4096 x 1024

    qkv_gemm<<<dim3(32, 24), 256, 0, stream>>>(x, W_attn, b_attn, qb, kb, vb);
    attn_kernel<<<dim3(32, 32), 256, 0, stream>>>(qb, kb, vb, yb);
    proj_gemm<<<dim3(32, 8), 256, 0, stream>>>(yb, W_proj, b_proj, out);
}

// Round 2
// 193.506 us; speedup vs baseline: 1.7542x; 1.7542x over previous
//
#include <hip/hip_runtime.h>

#define N_HEAD 16

typedef __attribute__((ext_vector_type(8))) __bf16 bf16x8;
typedef __attribute__((ext_vector_type(8))) short  s16x8;
typedef __attribute__((ext_vector_type(4))) short  s16x4;
typedef __attribute__((ext_vector_type(4))) float  f32x4;

static __device__ __forceinline__ short f2bf(float f) {
    unsigned u = __builtin_bit_cast(unsigned, f);
    unsigned r = (u + 0x7FFFu + ((u >> 16) & 1u)) >> 16;
    return (short)r;
}

static __device__ __forceinline__ void gload_lds16(const void* g, void* l) {
    __builtin_amdgcn_global_load_lds(
        (const __attribute__((address_space(1))) void*)g,
        (__attribute__((address_space(3))) void*)l, 16, 0, 0);
}

// ------------------------------------------------------------ pre-pass: X -> bf16
__global__ __launch_bounds__(256) void cvt_bf16(
    const float* __restrict__ X, short* __restrict__ Y, int n)
{
    int idx = blockIdx.x * 256 + threadIdx.x;
    size_t base = (size_t)idx * 8;
    if (base + 8 > (size_t)n) return;
    float4 f0 = *(const float4*)&X[base];
    float4 f1 = *(const float4*)&X[base + 4];
    s16x8 o;
    o[0] = f2bf(f0.x); o[1] = f2bf(f0.y); o[2] = f2bf(f0.z); o[3] = f2bf(f0.w);
    o[4] = f2bf(f1.x); o[5] = f2bf(f1.y); o[6] = f2bf(f1.z); o[7] = f2bf(f1.w);
    *(s16x8*)&Y[base] = o;
}

// ------------------------------------------- pre-pass: W [K][N] fp32 -> Wt [N][K] bf16
__global__ __launch_bounds__(256) void transpose_w(
    const float* __restrict__ W, short* __restrict__ Wt, int N, int K)
{
    __shared__ short Ts[64][72];
    const int n0 = blockIdx.x * 64, k0 = blockIdx.y * 64;
    const int tid = threadIdx.x;
    const int r = tid >> 4, c4 = (tid & 15) * 4;
#pragma unroll
    for (int i = 0; i < 4; ++i) {
        int row = r + i * 16;
        float4 f = *(const float4*)&W[(size_t)(k0 + row) * N + n0 + c4];
        s16x4 s = { f2bf(f.x), f2bf(f.y), f2bf(f.z), f2bf(f.w) };
        *(s16x4*)&Ts[row][c4] = s;
    }
    __syncthreads();
#pragma unroll
    for (int i = 0; i < 4; ++i) {
        int row = r + i * 16;       // output n offset
        s16x4 s = { Ts[c4 + 0][row], Ts[c4 + 1][row], Ts[c4 + 2][row], Ts[c4 + 3][row] };
        *(s16x4*)&Wt[(size_t)(n0 + row) * K + k0 + c4] = s;
    }
}

// ---------------------------------------------------------------- GEMM 1: qkv
// C[4096,3072] = Xb[4096,1024] · Wt[3072,1024]^T ; scatter to q/k/v (B,H,T,64)
__global__ __launch_bounds__(256) void qkv_gemm(
    const short* __restrict__ Xb,
    const short* __restrict__ Wt,
    const float* __restrict__ bias,
    short* __restrict__ Qo, short* __restrict__ Ko, short* __restrict__ Vo)
{
    __shared__ short As[128 * 32];
    __shared__ short Bs[128 * 32];
    const int tid = threadIdx.x, wave = tid >> 6, lane = tid & 63;
    const int row0 = blockIdx.x * 128, col0 = blockIdx.y * 128;
    const int srow = wave * 16 + (lane >> 2);
    const int scol = (lane & 3) * 8;
    const short* aS = Xb + (size_t)(row0 + srow) * 1024 + scol;
    const short* bS = Wt + (size_t)(col0 + srow) * 1024 + scol;
    short* aD = As + wave * 512;            // wave-uniform LDS dest (1 KiB/wave)
    short* bD = Bs + wave * 512;
    const int wr = (wave >> 1) * 64, wc = (wave & 1) * 64;
    const int arow = lane & 15, ksub = (lane >> 4) * 8;

    f32x4 acc[4][4] = {};

    for (int k0 = 0; k0 < 1024; k0 += 32) {
        gload_lds16(aS + k0,             aD);
        gload_lds16(aS + k0 + 64 * 1024, aD + 2048);
        gload_lds16(bS + k0,             bD);
        gload_lds16(bS + k0 + 64 * 1024, bD + 2048);
        __syncthreads();
        bf16x8 af[4], bfr[4];
#pragma unroll
        for (int i = 0; i < 4; ++i) af[i]  = *(const bf16x8*)&As[(wr + i * 16 + arow) * 32 + ksub];
#pragma unroll
        for (int j = 0; j < 4; ++j) bfr[j] = *(const bf16x8*)&Bs[(wc + j * 16 + arow) * 32 + ksub];
#pragma unroll
        for (int i = 0; i < 4; ++i)
#pragma unroll
            for (int j = 0; j < 4; ++j)
                acc[i][j] = __builtin_amdgcn_mfma_f32_16x16x32_bf16(af[i], bfr[j], acc[i][j], 0, 0, 0);
        __syncthreads();
    }

    const int ccol = lane & 15, crow = (lane >> 4) * 4;
#pragma unroll
    for (int i = 0; i < 4; ++i)
#pragma unroll
        for (int j = 0; j < 4; ++j)
#pragma unroll
            for (int r = 0; r < 4; ++r) {
                int m = row0 + wr + i * 16 + crow + r;
                int n = col0 + wc + j * 16 + ccol;
                float val = acc[i][j][r] + bias[n];
                int which = n >> 10;
                int nc = n & 1023;
                int head = nc >> 6, hd = nc & 63;
                int b = m >> 11, t = m & 2047;
                if (which == 0) val *= 0.125f;   // fold softmax scale into q
                short* dst = (which == 0) ? Qo : (which == 1) ? Ko : Vo;
                dst[((size_t)(b * N_HEAD + head) * 2048 + t) * 64 + hd] = f2bf(val);
            }
}

// ---------------------------------------------------------- flash attention
#define QBLK 64
#define KBLK 64
#define LDV (KBLK + 8)

__global__ __launch_bounds__(256) void attn_kernel(
    const short* __restrict__ Q, const short* __restrict__ K,
    const short* __restrict__ V, short* __restrict__ Y)
{
    __shared__ short Vs[64][LDV];       // [hd][key]  (transposed V tile)
    __shared__ short Ps[4][16][LDV];    // per-wave P tile [q][key]
    const int bh = blockIdx.x;          // 0..31
    const int q0 = blockIdx.y * QBLK;
    const int b = bh >> 4, h = bh & 15;
    const short* Qh = Q + (size_t)bh * 2048 * 64;
    const short* Kh = K + (size_t)bh * 2048 * 64;
    const short* Vh = V + (size_t)bh * 2048 * 64;
    const int tid = threadIdx.x, wave = tid >> 6, lane = tid & 63;
    const int qrow0 = q0 + wave * 16;
    const int arow = lane & 15, ksub = (lane >> 4) * 8;
    const int ccol = arow, crow = (lane >> 4) * 4;

    bf16x8 qf[2];
#pragma unroll
    for (int c = 0; c < 2; ++c)
        qf[c] = *(const bf16x8*)&Qh[(size_t)(qrow0 + arow) * 64 + c * 32 + ksub];

    f32x4 o[4] = {};
    float mrow[4] = { -1e30f, -1e30f, -1e30f, -1e30f };
    float lrow[4] = {};

    const int kv_end = q0 + QBLK;
    for (int kt = 0; kt < kv_end; kt += KBLK) {
        __syncthreads();
        {   // stage V transposed: Vs[hd][key]
            int hc = (tid & 7) * 8;
            int kr = tid >> 3;
#pragma unroll
            for (int i = 0; i < 2; ++i) {
                int kk = kr + i * 32;
                s16x8 vv = *(const s16x8*)&Vh[(size_t)(kt + kk) * 64 + hc];
#pragma unroll
                for (int e = 0; e < 8; ++e) Vs[hc + e][kk] = vv[e];
            }
        }
        __syncthreads();

        const bool need_mask = (kt + KBLK) > qrow0;
        f32x4 s[4];
#pragma unroll
        for (int kc = 0; kc < 4; ++kc) {
            f32x4 sv = {};
#pragma unroll
            for (int c = 0; c < 2; ++c) {
                bf16x8 kf = *(const bf16x8*)&Kh[(size_t)(kt + kc * 16 + arow) * 64 + c * 32 + ksub];
                sv = __builtin_amdgcn_mfma_f32_16x16x32_bf16(qf[c], kf, sv, 0, 0, 0);
            }
            if (need_mask) {
#pragma unroll
                for (int r = 0; r < 4; ++r) {
                    int key = kt + kc * 16 + ccol;
                    int qq  = qrow0 + crow + r;
                    if (key > qq) sv[r] = -3.0e38f;
                }
            }
            s[kc] = sv;
        }
        float p[4][4];
#pragma unroll
        for (int r = 0; r < 4; ++r) {
            float v0 = fmaxf(fmaxf(s[0][r], s[1][r]), fmaxf(s[2][r], s[3][r]));
#pragma unroll
            for (int msk = 1; msk < 16; msk <<= 1)
                v0 = fmaxf(v0, __shfl_xor(v0, msk));
            float mnew = fmaxf(mrow[r], v0);
            float sc = __expf(mrow[r] - mnew);
            mrow[r] = mnew;
            lrow[r] *= sc;
#pragma unroll
            for (int j = 0; j < 4; ++j) o[j][r] *= sc;
            float ssum = 0.f;
#pragma unroll
            for (int kc = 0; kc < 4; ++kc) {
                float pv = __expf(s[kc][r] - mnew);
                p[kc][r] = pv;
                ssum += pv;
            }
#pragma unroll
            for (int msk = 1; msk < 16; msk <<= 1)
                ssum += __shfl_xor(ssum, msk);
            lrow[r] += ssum;
        }
#pragma unroll
        for (int kc = 0; kc < 4; ++kc)
#pragma unroll
            for (int r = 0; r < 4; ++r)
                Ps[wave][crow + r][kc * 16 + ccol] = f2bf(p[kc][r]);
        __threadfence_block();
#pragma unroll
        for (int c = 0; c < 2; ++c) {
            bf16x8 pa = *(const bf16x8*)&Ps[wave][arow][c * 32 + ksub];
#pragma unroll
            for (int j = 0; j < 4; ++j) {
                bf16x8 vb = *(const bf16x8*)&Vs[j * 16 + arow][c * 32 + ksub];
                o[j] = __builtin_amdgcn_mfma_f32_16x16x32_bf16(pa, vb, o[j], 0, 0, 0);
            }
        }
    }

#pragma unroll
    for (int j = 0; j < 4; ++j)
#pragma unroll
        for (int r = 0; r < 4; ++r) {
            int t = qrow0 + crow + r;
            float val = o[j][r] / lrow[r];
            Y[((size_t)(b * 2048 + t)) * 1024 + h * 64 + j * 16 + ccol] = f2bf(val);
        }
}

// ---------------------------------------------------------------- GEMM 2: proj
// Out[4096,1024] = Yb[4096,1024] · Wpt[1024,1024]^T + bias  (fp32 out)
__global__ __launch_bounds__(256) void proj_gemm(
    const short* __restrict__ Yb,
    const short* __restrict__ Wpt,
    const float* __restrict__ bias,
    float* __restrict__ Out)
{
    __shared__ short As[128 * 32];
    __shared__ short Bs[128 * 32];
    const int tid = threadIdx.x, wave = tid >> 6, lane = tid & 63;
    const int row0 = blockIdx.x * 128, col0 = blockIdx.y * 128;
    const int srow = wave * 16 + (lane >> 2);
    const int scol = (lane & 3) * 8;
    const short* aS = Yb  + (size_t)(row0 + srow) * 1024 + scol;
    const short* bS = Wpt + (size_t)(col0 + srow) * 1024 + scol;
    short* aD = As + wave * 512;
    short* bD = Bs + wave * 512;
    const int wr = (wave >> 1) * 64, wc = (wave & 1) * 64;
    const int arow = lane & 15, ksub = (lane >> 4) * 8;

    f32x4 acc[4][4] = {};

    for (int k0 = 0; k0 < 1024; k0 += 32) {
        gload_lds16(aS + k0,             aD);
        gload_lds16(aS + k0 + 64 * 1024, aD + 2048);
        gload_lds16(bS + k0,             bD);
        gload_lds16(bS + k0 + 64 * 1024, bD + 2048);
        __syncthreads();
        bf16x8 af[4], bfr[4];
#pragma unroll
        for (int i = 0; i < 4; ++i) af[i]  = *(const bf16x8*)&As[(wr + i * 16 + arow) * 32 + ksub];
#pragma unroll
        for (int j = 0; j < 4; ++j) bfr[j] = *(const bf16x8*)&Bs[(wc + j * 16 + arow) * 32 + ksub];
#pragma unroll
        for (int i = 0; i < 4; ++i)
#pragma unroll
            for (int j = 0; j < 4; ++j)
                acc[i][j] = __builtin_amdgcn_mfma_f32_16x16x32_bf16(af[i], bfr[j], acc[i][j], 0, 0, 0);
        __syncthreads();
    }

    const int ccol = lane & 15, crow = (lane >> 4) * 4;
#pragma unroll
    for (int i = 0; i < 4; ++i)
#pragma unroll
        for (int j = 0; j < 4; ++j)
#pragma unroll
            for (int r = 0; r < 4; ++r) {
                int m = row0 + wr + i * 16 + crow + r;
                int n = col0 + wc + j * 16 + ccol;
                Out[(size_t)m * 1024 + n] = acc[i][j][r] + bias[n];
            }
}

// ------------------------------------------------------------------- launch
extern "C" void kernel_launch(void* const* d_in, const int* in_sizes, int n_in,
                              void* d_out, int out_size, void* d_ws, size_t ws_size,
                              hipStream_t stream) {
    const float* x      = (const float*)d_in[0];
    const float* W_attn = (const float*)d_in[1];
    const float* b_attn = (const float*)d_in[2];
    const float* W_proj = (const float*)d_in[3];
    const float* b_proj = (const float*)d_in[4];
    float* out = (float*)d_out;

    // workspace (shorts): Xb 4M | Wat 3M | Wpt 1M | q 4M | k 4M | v 4M  = 40 MB
    short* Xb  = (short*)d_ws;          // 4096x1024, dead after qkv -> aliased by yb
    short* Wat = Xb + 4194304;          // 3072x1024
    short* Wpt = Wat + 3145728;         // 1024x1024
    short* qb  = Wpt + 1048576;
    short* kb  = qb + 4194304;
    short* vb  = kb + 4194304;
    short* yb  = Xb;                    // alias: attn output (B,T,C) bf16

    cvt_bf16<<<2048, 256, 0, stream>>>(x, Xb, 4194304);
    transpose_w<<<dim3(48, 16), 256, 0, stream>>>(W_attn, Wat, 3072, 1024);
    transpose_w<<<dim3(16, 16), 256, 0, stream>>>(W_proj, Wpt, 1024, 1024);
    qkv_gemm<<<dim3(32, 24), 256, 0, stream>>>(Xb, Wat, b_attn, qb, kb, vb);
    attn_kernel<<<dim3(32, 32), 256, 0, stream>>>(qb, kb, vb, yb);
    proj_gemm<<<dim3(32, 8), 256, 0, stream>>>(yb, Wpt, b_proj, out);
}

// Round 3
// 165.097 us; speedup vs baseline: 2.0561x; 1.1721x over previous
//
#include <hip/hip_runtime.h>

#define N_HEAD 16

typedef __attribute__((ext_vector_type(8))) __bf16 bf16x8;
typedef __attribute__((ext_vector_type(8))) short  s16x8;
typedef __attribute__((ext_vector_type(4))) short  s16x4;
typedef __attribute__((ext_vector_type(4))) float  f32x4;

static __device__ __forceinline__ short f2bf(float f) {
    unsigned u = __builtin_bit_cast(unsigned, f);
    unsigned r = (u + 0x7FFFu + ((u >> 16) & 1u)) >> 16;
    return (short)r;
}

static __device__ __forceinline__ void gload_lds16(const void* g, void* l) {
    __builtin_amdgcn_global_load_lds(
        (const __attribute__((address_space(1))) void*)g,
        (__attribute__((address_space(3))) void*)l, 16, 0, 0);
}

// ------------------------------------------------------------ pre-pass: X -> bf16
__global__ __launch_bounds__(256) void cvt_bf16(
    const float* __restrict__ X, short* __restrict__ Y, int n)
{
    int idx = blockIdx.x * 256 + threadIdx.x;
    size_t base = (size_t)idx * 8;
    if (base + 8 > (size_t)n) return;
    float4 f0 = *(const float4*)&X[base];
    float4 f1 = *(const float4*)&X[base + 4];
    s16x8 o;
    o[0] = f2bf(f0.x); o[1] = f2bf(f0.y); o[2] = f2bf(f0.z); o[3] = f2bf(f0.w);
    o[4] = f2bf(f1.x); o[5] = f2bf(f1.y); o[6] = f2bf(f1.z); o[7] = f2bf(f1.w);
    *(s16x8*)&Y[base] = o;
}

// ------------------------------------------- pre-pass: W [K][N] fp32 -> Wt [N][K] bf16
__global__ __launch_bounds__(256) void transpose_w(
    const float* __restrict__ W, short* __restrict__ Wt, int N, int K)
{
    __shared__ short Ts[64][72];
    const int n0 = blockIdx.x * 64, k0 = blockIdx.y * 64;
    const int tid = threadIdx.x;
    const int r = tid >> 4, c4 = (tid & 15) * 4;
#pragma unroll
    for (int i = 0; i < 4; ++i) {
        int row = r + i * 16;
        float4 f = *(const float4*)&W[(size_t)(k0 + row) * N + n0 + c4];
        s16x4 s = { f2bf(f.x), f2bf(f.y), f2bf(f.z), f2bf(f.w) };
        *(s16x4*)&Ts[row][c4] = s;
    }
    __syncthreads();
#pragma unroll
    for (int i = 0; i < 4; ++i) {
        int row = r + i * 16;
        s16x4 s = { Ts[c4 + 0][row], Ts[c4 + 1][row], Ts[c4 + 2][row], Ts[c4 + 3][row] };
        *(s16x4*)&Wt[(size_t)(n0 + row) * K + k0 + c4] = s;
    }
}

// ---------------------------------------------------------------- GEMM 1: qkv
// C[4096,3072] = Xb[4096,1024] · Wt[3072,1024]^T ; scatter q/k (B,H,T,64), v (B,H,64,T)
__global__ __launch_bounds__(256) void qkv_gemm(
    const short* __restrict__ Xb,
    const short* __restrict__ Wt,
    const float* __restrict__ bias,
    short* __restrict__ Qo, short* __restrict__ Ko, short* __restrict__ Vo)
{
    __shared__ short As[128 * 32];
    __shared__ short Bs[128 * 32];
    const int tid = threadIdx.x, wave = tid >> 6, lane = tid & 63;
    const int row0 = blockIdx.x * 128, col0 = blockIdx.y * 128;
    const int srow = wave * 16 + (lane >> 2);
    const int scol = (lane & 3) * 8;
    const short* aS = Xb + (size_t)(row0 + srow) * 1024 + scol;
    const short* bS = Wt + (size_t)(col0 + srow) * 1024 + scol;
    short* aD = As + wave * 512;
    short* bD = Bs + wave * 512;
    const int wr = (wave >> 1) * 64, wc = (wave & 1) * 64;
    const int arow = lane & 15, ksub = (lane >> 4) * 8;

    f32x4 acc[4][4] = {};

    for (int k0 = 0; k0 < 1024; k0 += 32) {
        gload_lds16(aS + k0,             aD);
        gload_lds16(aS + k0 + 64 * 1024, aD + 2048);
        gload_lds16(bS + k0,             bD);
        gload_lds16(bS + k0 + 64 * 1024, bD + 2048);
        __syncthreads();
        bf16x8 af[4], bfr[4];
#pragma unroll
        for (int i = 0; i < 4; ++i) af[i]  = *(const bf16x8*)&As[(wr + i * 16 + arow) * 32 + ksub];
#pragma unroll
        for (int j = 0; j < 4; ++j) bfr[j] = *(const bf16x8*)&Bs[(wc + j * 16 + arow) * 32 + ksub];
#pragma unroll
        for (int i = 0; i < 4; ++i)
#pragma unroll
            for (int j = 0; j < 4; ++j)
                acc[i][j] = __builtin_amdgcn_mfma_f32_16x16x32_bf16(af[i], bfr[j], acc[i][j], 0, 0, 0);
        __syncthreads();
    }

    const int ccol = lane & 15, crow = (lane >> 4) * 4;
#pragma unroll
    for (int i = 0; i < 4; ++i)
#pragma unroll
        for (int j = 0; j < 4; ++j)
#pragma unroll
            for (int r = 0; r < 4; ++r) {
                int m = row0 + wr + i * 16 + crow + r;
                int n = col0 + wc + j * 16 + ccol;
                float val = acc[i][j][r] + bias[n];
                int which = n >> 10;
                int nc = n & 1023;
                int head = nc >> 6, hd = nc & 63;
                int b = m >> 11, t = m & 2047;
                if (which == 0) {
                    Qo[((size_t)(b * N_HEAD + head) * 2048 + t) * 64 + hd] = f2bf(val * 0.125f);
                } else if (which == 1) {
                    Ko[((size_t)(b * N_HEAD + head) * 2048 + t) * 64 + hd] = f2bf(val);
                } else {
                    // V stored TRANSPOSED: [bh][d][t]
                    Vo[((size_t)(b * N_HEAD + head) * 64 + hd) * 2048 + t] = f2bf(val);
                }
            }
}

// ---------------------------------------------------------- flash attention v2
// block: 4 waves x 32 q-rows = 128 q-rows; K,V^T staged in LDS (XOR-swizzled via
// pre-swizzled global source, linear gload_lds dest); P via swizzled per-wave LDS.
__global__ __launch_bounds__(256) void attn_kernel(
    const short* __restrict__ Q, const short* __restrict__ K,
    const short* __restrict__ Vt, short* __restrict__ Y)
{
    __shared__ short Ks[64 * 64];        // [key][d], chunk ^= (key&7)
    __shared__ short Vs[64 * 64];        // [d][key], chunk ^= (d&7)
    __shared__ short Ps[4 * 32 * 64];    // per-wave [q][key], chunk ^= (q&7)
    const int bh = blockIdx.x;
    const int qt = gridDim.y - 1 - blockIdx.y;   // big tiles first
    const int q0 = qt * 128;
    const int b = bh >> 4, h = bh & 15;
    const short* Qh = Q  + (size_t)bh * 2048 * 64;
    const short* Kh = K  + (size_t)bh * 2048 * 64;
    const short* Vh = Vt + (size_t)bh * 64 * 2048;
    const int tid = threadIdx.x, wave = tid >> 6, lane = tid & 63;
    const int qrow0 = q0 + wave * 32;
    const int arow = lane & 15, g = lane >> 4, ksub = g * 8;
    const int ccol = arow, crow = g * 4;

    // staging addresses: wave covers rows [wave*16, wave*16+16), 2 calls (s=0,1)
    const int srow = wave * 16 + (lane >> 3);           // s=0 row
    const int schunk = 8 * ((lane & 7) ^ (srow & 7));   // same for s=0,1 (rows differ by 8)
    const short* kSrc = Kh + (size_t)srow * 64 + schunk;
    const short* vSrc = Vh + (size_t)srow * 2048 + schunk;
    short* kDst = Ks + wave * 1024;
    short* vDst = Vs + wave * 1024;
    short* Pw = Ps + wave * 2048;

    bf16x8 qfr[2][2];
#pragma unroll
    for (int qf = 0; qf < 2; ++qf)
#pragma unroll
        for (int c = 0; c < 2; ++c)
            qfr[qf][c] = *(const bf16x8*)&Qh[(size_t)(qrow0 + qf * 16 + arow) * 64 + c * 32 + ksub];

    f32x4 o[2][4] = {};
    float mrow[2][4], lrow[2][4] = {};
#pragma unroll
    for (int qf = 0; qf < 2; ++qf)
#pragma unroll
        for (int r = 0; r < 4; ++r) mrow[qf][r] = -1e30f;

    const int kv_end = q0 + 128;
    for (int kt = 0; kt < kv_end; kt += 64) {
        __syncthreads();     // previous tile fully consumed
        gload_lds16(kSrc + (size_t)kt * 64,        kDst);
        gload_lds16(kSrc + (size_t)kt * 64 + 512,  kDst + 512);    // +8 rows
        gload_lds16(vSrc + kt,                     vDst);
        gload_lds16(vSrc + kt + 8 * 2048,          vDst + 512);
        __syncthreads();     // staging complete

        if (kt <= qrow0 + 31) {          // wave-uniform: skip fully-masked tiles
            const bool need_mask = (kt + 64) > qrow0;
            f32x4 s[2][4] = {};
#pragma unroll
            for (int kc = 0; kc < 4; ++kc) {
                int key = kc * 16 + arow;
                int xr = (key & 7);
#pragma unroll
                for (int c = 0; c < 2; ++c) {
                    bf16x8 kf = *(const bf16x8*)&Ks[key * 64 + (((c * 4 + g) ^ xr) * 8)];
#pragma unroll
                    for (int qf = 0; qf < 2; ++qf)
                        s[qf][kc] = __builtin_amdgcn_mfma_f32_16x16x32_bf16(qfr[qf][c], kf, s[qf][kc], 0, 0, 0);
                }
            }
            if (need_mask) {
#pragma unroll
                for (int qf = 0; qf < 2; ++qf)
#pragma unroll
                    for (int kc = 0; kc < 4; ++kc)
#pragma unroll
                        for (int r = 0; r < 4; ++r) {
                            int key = kt + kc * 16 + ccol;
                            int qq  = qrow0 + qf * 16 + crow + r;
                            if (key > qq) s[qf][kc][r] = -3.0e38f;
                        }
            }
#pragma unroll
            for (int qf = 0; qf < 2; ++qf)
#pragma unroll
                for (int r = 0; r < 4; ++r) {
                    float v0 = fmaxf(fmaxf(s[qf][0][r], s[qf][1][r]), fmaxf(s[qf][2][r], s[qf][3][r]));
#pragma unroll
                    for (int msk = 1; msk < 16; msk <<= 1)
                        v0 = fmaxf(v0, __shfl_xor(v0, msk));
                    float mnew = fmaxf(mrow[qf][r], v0);
                    float sc = __expf(mrow[qf][r] - mnew);
                    mrow[qf][r] = mnew;
                    lrow[qf][r] *= sc;
#pragma unroll
                    for (int j = 0; j < 4; ++j) o[qf][j][r] *= sc;
                    float ssum = 0.f;
                    int q = qf * 16 + crow + r;
                    int qx = q & 7;
                    int pbase = q * 64 + (ccol & 7);
#pragma unroll
                    for (int kc = 0; kc < 4; ++kc) {
                        float pv = __expf(s[qf][kc][r] - mnew);
                        ssum += pv;
                        Pw[pbase + (((kc * 2 + (ccol >> 3)) ^ qx) * 8)] = f2bf(pv);
                    }
#pragma unroll
                    for (int msk = 1; msk < 16; msk <<= 1)
                        ssum += __shfl_xor(ssum, msk);
                    lrow[qf][r] += ssum;
                }
            __threadfence_block();       // order same-wave P write -> P read
#pragma unroll
            for (int c = 0; c < 2; ++c) {
                bf16x8 pa[2];
#pragma unroll
                for (int qf = 0; qf < 2; ++qf) {
                    int q = qf * 16 + arow;
                    pa[qf] = *(const bf16x8*)&Pw[q * 64 + (((c * 4 + g) ^ (q & 7)) * 8)];
                }
#pragma unroll
                for (int j = 0; j < 4; ++j) {
                    int d = j * 16 + arow;
                    bf16x8 vf = *(const bf16x8*)&Vs[d * 64 + (((c * 4 + g) ^ (d & 7)) * 8)];
#pragma unroll
                    for (int qf = 0; qf < 2; ++qf)
                        o[qf][j] = __builtin_amdgcn_mfma_f32_16x16x32_bf16(pa[qf], vf, o[qf][j], 0, 0, 0);
                }
            }
        }
    }

#pragma unroll
    for (int qf = 0; qf < 2; ++qf)
#pragma unroll
        for (int j = 0; j < 4; ++j)
#pragma unroll
            for (int r = 0; r < 4; ++r) {
                int t = qrow0 + qf * 16 + crow + r;
                float val = o[qf][j][r] / lrow[qf][r];
                Y[((size_t)(b * 2048 + t)) * 1024 + h * 64 + j * 16 + ccol] = f2bf(val);
            }
}

// ---------------------------------------------------------------- GEMM 2: proj
__global__ __launch_bounds__(256) void proj_gemm(
    const short* __restrict__ Yb,
    const short* __restrict__ Wpt,
    const float* __restrict__ bias,
    float* __restrict__ Out)
{
    __shared__ short As[128 * 32];
    __shared__ short Bs[128 * 32];
    const int tid = threadIdx.x, wave = tid >> 6, lane = tid & 63;
    const int row0 = blockIdx.x * 128, col0 = blockIdx.y * 128;
    const int srow = wave * 16 + (lane >> 2);
    const int scol = (lane & 3) * 8;
    const short* aS = Yb  + (size_t)(row0 + srow) * 1024 + scol;
    const short* bS = Wpt + (size_t)(col0 + srow) * 1024 + scol;
    short* aD = As + wave * 512;
    short* bD = Bs + wave * 512;
    const int wr = (wave >> 1) * 64, wc = (wave & 1) * 64;
    const int arow = lane & 15, ksub = (lane >> 4) * 8;

    f32x4 acc[4][4] = {};

    for (int k0 = 0; k0 < 1024; k0 += 32) {
        gload_lds16(aS + k0,             aD);
        gload_lds16(aS + k0 + 64 * 1024, aD + 2048);
        gload_lds16(bS + k0,             bD);
        gload_lds16(bS + k0 + 64 * 1024, bD + 2048);
        __syncthreads();
        bf16x8 af[4], bfr[4];
#pragma unroll
        for (int i = 0; i < 4; ++i) af[i]  = *(const bf16x8*)&As[(wr + i * 16 + arow) * 32 + ksub];
#pragma unroll
        for (int j = 0; j < 4; ++j) bfr[j] = *(const bf16x8*)&Bs[(wc + j * 16 + arow) * 32 + ksub];
#pragma unroll
        for (int i = 0; i < 4; ++i)
#pragma unroll
            for (int j = 0; j < 4; ++j)
                acc[i][j] = __builtin_amdgcn_mfma_f32_16x16x32_bf16(af[i], bfr[j], acc[i][j], 0, 0, 0);
        __syncthreads();
    }

    const int ccol = lane & 15, crow = (lane >> 4) * 4;
#pragma unroll
    for (int i = 0; i < 4; ++i)
#pragma unroll
        for (int j = 0; j < 4; ++j)
#pragma unroll
            for (int r = 0; r < 4; ++r) {
                int m = row0 + wr + i * 16 + crow + r;
                int n = col0 + wc + j * 16 + ccol;
                Out[(size_t)m * 1024 + n] = acc[i][j][r] + bias[n];
            }
}

// ------------------------------------------------------------------- launch
extern "C" void kernel_launch(void* const* d_in, const int* in_sizes, int n_in,
                              void* d_out, int out_size, void* d_ws, size_t ws_size,
                              hipStream_t stream) {
    const float* x      = (const float*)d_in[0];
    const float* W_attn = (const float*)d_in[1];
    const float* b_attn = (const float*)d_in[2];
    const float* W_proj = (const float*)d_in[3];
    const float* b_proj = (const float*)d_in[4];
    float* out = (float*)d_out;

    short* Xb  = (short*)d_ws;          // 4096x1024, dead after qkv -> aliased by yb
    short* Wat = Xb + 4194304;          // 3072x1024
    short* Wpt = Wat + 3145728;         // 1024x1024
    short* qb  = Wpt + 1048576;
    short* kb  = qb + 4194304;
    short* vb  = kb + 4194304;          // V^T: [bh][d][t]
    short* yb  = Xb;                    // alias: attn output (B,T,C) bf16

    cvt_bf16<<<2048, 256, 0, stream>>>(x, Xb, 4194304);
    transpose_w<<<dim3(48, 16), 256, 0, stream>>>(W_attn, Wat, 3072, 1024);
    transpose_w<<<dim3(16, 16), 256, 0, stream>>>(W_proj, Wpt, 1024, 1024);
    qkv_gemm<<<dim3(32, 24), 256, 0, stream>>>(Xb, Wat, b_attn, qb, kb, vb);
    attn_kernel<<<dim3(32, 16), 256, 0, stream>>>(qb, kb, vb, yb);
    proj_gemm<<<dim3(32, 8), 256, 0, stream>>>(yb, Wpt, b_proj, out);
}

// Round 4
// 136.952 us; speedup vs baseline: 2.4786x; 1.2055x over previous
//
#include <hip/hip_runtime.h>

#define N_HEAD 16

typedef __attribute__((ext_vector_type(8))) __bf16 bf16x8;
typedef __attribute__((ext_vector_type(8))) short  s16x8;
typedef __attribute__((ext_vector_type(4))) short  s16x4;
typedef __attribute__((ext_vector_type(4))) float  f32x4;

#if __has_builtin(__builtin_amdgcn_exp2f)
#define EXP2(x) __builtin_amdgcn_exp2f(x)
#else
#define EXP2(x) exp2f(x)
#endif
#if __has_builtin(__builtin_amdgcn_rcpf)
#define RCP(x) __builtin_amdgcn_rcpf(x)
#else
#define RCP(x) (1.0f / (x))
#endif

static __device__ __forceinline__ short f2bf(float f) {
    unsigned u = __builtin_bit_cast(unsigned, f);
    unsigned r = (u + 0x7FFFu + ((u >> 16) & 1u)) >> 16;
    return (short)r;
}

static __device__ __forceinline__ void gload_lds16(const void* g, void* l) {
    __builtin_amdgcn_global_load_lds(
        (const __attribute__((address_space(1))) void*)g,
        (__attribute__((address_space(3))) void*)l, 16, 0, 0);
}

// ------------------------------------------------------------ pre-pass: X -> bf16
__global__ __launch_bounds__(256) void cvt_bf16(
    const float* __restrict__ X, short* __restrict__ Y, int n)
{
    int idx = blockIdx.x * 256 + threadIdx.x;
    size_t base = (size_t)idx * 8;
    if (base + 8 > (size_t)n) return;
    float4 f0 = *(const float4*)&X[base];
    float4 f1 = *(const float4*)&X[base + 4];
    s16x8 o;
    o[0] = f2bf(f0.x); o[1] = f2bf(f0.y); o[2] = f2bf(f0.z); o[3] = f2bf(f0.w);
    o[4] = f2bf(f1.x); o[5] = f2bf(f1.y); o[6] = f2bf(f1.z); o[7] = f2bf(f1.w);
    *(s16x8*)&Y[base] = o;
}

// ------------------------------------------- pre-pass: W [K][N] fp32 -> Wt [N][K] bf16
__global__ __launch_bounds__(256) void transpose_w(
    const float* __restrict__ W, short* __restrict__ Wt, int N, int K)
{
    __shared__ short Ts[64][72];
    const int n0 = blockIdx.x * 64, k0 = blockIdx.y * 64;
    const int tid = threadIdx.x;
    const int r = tid >> 4, c4 = (tid & 15) * 4;
#pragma unroll
    for (int i = 0; i < 4; ++i) {
        int row = r + i * 16;
        float4 f = *(const float4*)&W[(size_t)(k0 + row) * N + n0 + c4];
        s16x4 s = { f2bf(f.x), f2bf(f.y), f2bf(f.z), f2bf(f.w) };
        *(s16x4*)&Ts[row][c4] = s;
    }
    __syncthreads();
#pragma unroll
    for (int i = 0; i < 4; ++i) {
        int row = r + i * 16;
        s16x4 s = { Ts[c4 + 0][row], Ts[c4 + 1][row], Ts[c4 + 2][row], Ts[c4 + 3][row] };
        *(s16x4*)&Wt[(size_t)(n0 + row) * K + k0 + c4] = s;
    }
}

// ---------------------------------------------------------------- GEMM 1: qkv
// C[4096,3072] = Xb[4096,1024] · Wt[3072,1024]^T ; scatter q/k (B,H,T,64), v (B,H,64,T)
// q is pre-scaled by 0.125 * log2(e) so attention can use exp2 directly.
__global__ __launch_bounds__(256) void qkv_gemm(
    const short* __restrict__ Xb,
    const short* __restrict__ Wt,
    const float* __restrict__ bias,
    short* __restrict__ Qo, short* __restrict__ Ko, short* __restrict__ Vo)
{
    __shared__ short As[2][128 * 32];
    __shared__ short Bs[2][128 * 32];
    const int tid = threadIdx.x, wave = tid >> 6, lane = tid & 63;
    const int row0 = blockIdx.x * 128, col0 = blockIdx.y * 128;
    const int srow = wave * 16 + (lane >> 2);
    const int scol = (lane & 3) * 8;
    const short* aS = Xb + (size_t)(row0 + srow) * 1024 + scol;
    const short* bS = Wt + (size_t)(col0 + srow) * 1024 + scol;
    const int woff = wave * 512;
    const int wr = (wave >> 1) * 64, wc = (wave & 1) * 64;
    const int arow = lane & 15, ksub = (lane >> 4) * 8;

    f32x4 acc[4][4] = {};

    gload_lds16(aS,             As[0] + woff);
    gload_lds16(aS + 64 * 1024, As[0] + woff + 2048);
    gload_lds16(bS,             Bs[0] + woff);
    gload_lds16(bS + 64 * 1024, Bs[0] + woff + 2048);
    __syncthreads();

    int cur = 0;
    for (int k0 = 0; k0 < 1024; k0 += 32) {
        if (k0 + 32 < 1024) {
            gload_lds16(aS + k0 + 32,             As[cur ^ 1] + woff);
            gload_lds16(aS + k0 + 32 + 64 * 1024, As[cur ^ 1] + woff + 2048);
            gload_lds16(bS + k0 + 32,             Bs[cur ^ 1] + woff);
            gload_lds16(bS + k0 + 32 + 64 * 1024, Bs[cur ^ 1] + woff + 2048);
        }
        bf16x8 af[4], bfr[4];
#pragma unroll
        for (int i = 0; i < 4; ++i) af[i]  = *(const bf16x8*)&As[cur][(wr + i * 16 + arow) * 32 + ksub];
#pragma unroll
        for (int j = 0; j < 4; ++j) bfr[j] = *(const bf16x8*)&Bs[cur][(wc + j * 16 + arow) * 32 + ksub];
#pragma unroll
        for (int i = 0; i < 4; ++i)
#pragma unroll
            for (int j = 0; j < 4; ++j)
                acc[i][j] = __builtin_amdgcn_mfma_f32_16x16x32_bf16(af[i], bfr[j], acc[i][j], 0, 0, 0);
        __syncthreads();
        cur ^= 1;
    }

    const int ccol = lane & 15, crow = (lane >> 4) * 4;
#pragma unroll
    for (int i = 0; i < 4; ++i)
#pragma unroll
        for (int j = 0; j < 4; ++j)
#pragma unroll
            for (int r = 0; r < 4; ++r) {
                int m = row0 + wr + i * 16 + crow + r;
                int n = col0 + wc + j * 16 + ccol;
                float val = acc[i][j][r] + bias[n];
                int which = n >> 10;
                int nc = n & 1023;
                int head = nc >> 6, hd = nc & 63;
                int b = m >> 11, t = m & 2047;
                if (which == 0) {
                    Qo[((size_t)(b * N_HEAD + head) * 2048 + t) * 64 + hd] = f2bf(val * 0.18033688f);
                } else if (which == 1) {
                    Ko[((size_t)(b * N_HEAD + head) * 2048 + t) * 64 + hd] = f2bf(val);
                } else {
                    Vo[((size_t)(b * N_HEAD + head) * 64 + hd) * 2048 + t] = f2bf(val);
                }
            }
}

// ---------------------------------------------------------- flash attention v3
// 4 waves x 32 q-rows; K,V^T double-buffered in LDS (pre-swizzled global source,
// linear gload_lds dest, XOR-swizzled reads); no-max softmax (norm-bounded logits),
// deferred l-reduction; 1 barrier per kv tile.
__global__ __launch_bounds__(256) void attn_kernel(
    const short* __restrict__ Q, const short* __restrict__ K,
    const short* __restrict__ Vt, short* __restrict__ Y)
{
    __shared__ short Ks[2][64 * 64];
    __shared__ short Vs[2][64 * 64];
    __shared__ short Ps[4 * 32 * 64];
    const int bh = blockIdx.x;
    const int qt = gridDim.y - 1 - blockIdx.y;   // big tiles dispatched first
    const int q0 = qt * 128;
    const int b = bh >> 4, h = bh & 15;
    const short* Qh = Q  + (size_t)bh * 2048 * 64;
    const short* Kh = K  + (size_t)bh * 2048 * 64;
    const short* Vh = Vt + (size_t)bh * 64 * 2048;
    const int tid = threadIdx.x, wave = tid >> 6, lane = tid & 63;
    const int qrow0 = q0 + wave * 32;
    const int arow = lane & 15, g = lane >> 4, ksub = g * 8;
    const int ccol = arow, crow = g * 4;

    const int srow = wave * 16 + (lane >> 3);
    const int schunk = 8 * ((lane & 7) ^ (srow & 7));
    const short* kSrc = Kh + (size_t)srow * 64 + schunk;
    const short* vSrc = Vh + (size_t)srow * 2048 + schunk;
    short* Pw = Ps + wave * 2048;

    bf16x8 qfr[2][2];
#pragma unroll
    for (int qf = 0; qf < 2; ++qf)
#pragma unroll
        for (int c = 0; c < 2; ++c)
            qfr[qf][c] = *(const bf16x8*)&Qh[(size_t)(qrow0 + qf * 16 + arow) * 64 + c * 32 + ksub];

    f32x4 o[2][4] = {};
    float lsum[2][4] = {};

    const int nt = (q0 + 128) >> 6;

    // prologue: stage tile 0 into buffer 0
    gload_lds16(kSrc,            Ks[0] + wave * 1024);
    gload_lds16(kSrc + 512,      Ks[0] + wave * 1024 + 512);
    gload_lds16(vSrc,            Vs[0] + wave * 1024);
    gload_lds16(vSrc + 8 * 2048, Vs[0] + wave * 1024 + 512);
    __syncthreads();

    int cur = 0;
    for (int t = 0; t < nt; ++t) {
        const int kt = t << 6;
        if (t + 1 < nt) {            // prefetch next tile into alternate buffer
            const int kn = kt + 64;
            short* kD = Ks[cur ^ 1] + wave * 1024;
            short* vD = Vs[cur ^ 1] + wave * 1024;
            gload_lds16(kSrc + (size_t)kn * 64,       kD);
            gload_lds16(kSrc + (size_t)kn * 64 + 512, kD + 512);
            gload_lds16(vSrc + kn,                    vD);
            gload_lds16(vSrc + kn + 8 * 2048,         vD + 512);
        }
        if (kt <= qrow0 + 31) {      // wave-uniform skip of fully-masked tiles
            const short* Kc = Ks[cur];
            const short* Vc = Vs[cur];
            const bool need_mask = (kt + 64) > qrow0;
            f32x4 s[2][4] = {};
#pragma unroll
            for (int kc = 0; kc < 4; ++kc) {
                int key = kc * 16 + arow;
                int xr = key & 7;
#pragma unroll
                for (int c = 0; c < 2; ++c) {
                    bf16x8 kf = *(const bf16x8*)&Kc[key * 64 + (((c * 4 + g) ^ xr) * 8)];
#pragma unroll
                    for (int qf = 0; qf < 2; ++qf)
                        s[qf][kc] = __builtin_amdgcn_mfma_f32_16x16x32_bf16(qfr[qf][c], kf, s[qf][kc], 0, 0, 0);
                }
            }
            if (need_mask) {
#pragma unroll
                for (int qf = 0; qf < 2; ++qf)
#pragma unroll
                    for (int kc = 0; kc < 4; ++kc)
#pragma unroll
                        for (int r = 0; r < 4; ++r) {
                            int key = kt + kc * 16 + ccol;
                            int qq  = qrow0 + qf * 16 + crow + r;
                            if (key > qq) s[qf][kc][r] = -3.0e38f;
                        }
            }
            // no-max softmax: p = 2^s' (s' pre-scaled by log2e); per-lane partial l
#pragma unroll
            for (int qf = 0; qf < 2; ++qf)
#pragma unroll
                for (int r = 0; r < 4; ++r) {
                    int q = qf * 16 + crow + r;
                    int qx = q & 7;
                    int pbase = q * 64 + (ccol & 7);
#pragma unroll
                    for (int kc = 0; kc < 4; ++kc) {
                        float p = EXP2(s[qf][kc][r]);
                        lsum[qf][r] += p;
                        Pw[pbase + (((kc * 2 + (ccol >> 3)) ^ qx) * 8)] = f2bf(p);
                    }
                }
            __threadfence_block();   // order same-wave P write -> P read
#pragma unroll
            for (int c = 0; c < 2; ++c) {
                bf16x8 pa[2];
#pragma unroll
                for (int qf = 0; qf < 2; ++qf) {
                    int q = qf * 16 + arow;
                    pa[qf] = *(const bf16x8*)&Pw[q * 64 + (((c * 4 + g) ^ (q & 7)) * 8)];
                }
#pragma unroll
                for (int j = 0; j < 4; ++j) {
                    int d = j * 16 + arow;
                    bf16x8 vf = *(const bf16x8*)&Vc[d * 64 + (((c * 4 + g) ^ (d & 7)) * 8)];
#pragma unroll
                    for (int qf = 0; qf < 2; ++qf)
                        o[qf][j] = __builtin_amdgcn_mfma_f32_16x16x32_bf16(pa[qf], vf, o[qf][j], 0, 0, 0);
                }
            }
        }
        __syncthreads();
        cur ^= 1;
    }

    // epilogue: one cross-lane l-reduction, then normalize + store
#pragma unroll
    for (int qf = 0; qf < 2; ++qf)
#pragma unroll
        for (int r = 0; r < 4; ++r) {
            float l = lsum[qf][r];
#pragma unroll
            for (int msk = 1; msk < 16; msk <<= 1)
                l += __shfl_xor(l, msk);
            float li = RCP(l);
            int t = qrow0 + qf * 16 + crow + r;
#pragma unroll
            for (int j = 0; j < 4; ++j)
                Y[((size_t)(b * 2048 + t)) * 1024 + h * 64 + j * 16 + ccol] = f2bf(o[qf][j][r] * li);
        }
}

// ---------------------------------------------------------------- GEMM 2: proj
__global__ __launch_bounds__(256) void proj_gemm(
    const short* __restrict__ Yb,
    const short* __restrict__ Wpt,
    const float* __restrict__ bias,
    float* __restrict__ Out)
{
    __shared__ short As[2][128 * 32];
    __shared__ short Bs[2][128 * 32];
    const int tid = threadIdx.x, wave = tid >> 6, lane = tid & 63;
    const int row0 = blockIdx.x * 128, col0 = blockIdx.y * 128;
    const int srow = wave * 16 + (lane >> 2);
    const int scol = (lane & 3) * 8;
    const short* aS = Yb  + (size_t)(row0 + srow) * 1024 + scol;
    const short* bS = Wpt + (size_t)(col0 + srow) * 1024 + scol;
    const int woff = wave * 512;
    const int wr = (wave >> 1) * 64, wc = (wave & 1) * 64;
    const int arow = lane & 15, ksub = (lane >> 4) * 8;

    f32x4 acc[4][4] = {};

    gload_lds16(aS,             As[0] + woff);
    gload_lds16(aS + 64 * 1024, As[0] + woff + 2048);
    gload_lds16(bS,             Bs[0] + woff);
    gload_lds16(bS + 64 * 1024, Bs[0] + woff + 2048);
    __syncthreads();

    int cur = 0;
    for (int k0 = 0; k0 < 1024; k0 += 32) {
        if (k0 + 32 < 1024) {
            gload_lds16(aS + k0 + 32,             As[cur ^ 1] + woff);
            gload_lds16(aS + k0 + 32 + 64 * 1024, As[cur ^ 1] + woff + 2048);
            gload_lds16(bS + k0 + 32,             Bs[cur ^ 1] + woff);
            gload_lds16(bS + k0 + 32 + 64 * 1024, Bs[cur ^ 1] + woff + 2048);
        }
        bf16x8 af[4], bfr[4];
#pragma unroll
        for (int i = 0; i < 4; ++i) af[i]  = *(const bf16x8*)&As[cur][(wr + i * 16 + arow) * 32 + ksub];
#pragma unroll
        for (int j = 0; j < 4; ++j) bfr[j] = *(const bf16x8*)&Bs[cur][(wc + j * 16 + arow) * 32 + ksub];
#pragma unroll
        for (int i = 0; i < 4; ++i)
#pragma unroll
            for (int j = 0; j < 4; ++j)
                acc[i][j] = __builtin_amdgcn_mfma_f32_16x16x32_bf16(af[i], bfr[j], acc[i][j], 0, 0, 0);
        __syncthreads();
        cur ^= 1;
    }

    const int ccol = lane & 15, crow = (lane >> 4) * 4;
#pragma unroll
    for (int i = 0; i < 4; ++i)
#pragma unroll
        for (int j = 0; j < 4; ++j)
#pragma unroll
            for (int r = 0; r < 4; ++r) {
                int m = row0 + wr + i * 16 + crow + r;
                int n = col0 + wc + j * 16 + ccol;
                Out[(size_t)m * 1024 + n] = acc[i][j][r] + bias[n];
            }
}

// ------------------------------------------------------------------- launch
extern "C" void kernel_launch(void* const* d_in, const int* in_sizes, int n_in,
                              void* d_out, int out_size, void* d_ws, size_t ws_size,
                              hipStream_t stream) {
    const float* x      = (const float*)d_in[0];
    const float* W_attn = (const float*)d_in[1];
    const float* b_attn = (const float*)d_in[2];
    const float* W_proj = (const float*)d_in[3];
    const float* b_proj = (const float*)d_in[4];
    float* out = (float*)d_out;

    short* Xb  = (short*)d_ws;          // 4096x1024, dead after qkv -> aliased by yb
    short* Wat = Xb + 4194304;          // 3072x1024
    short* Wpt = Wat + 3145728;         // 1024x1024
    short* qb  = Wpt + 1048576;
    short* kb  = qb + 4194304;
    short* vb  = kb + 4194304;          // V^T: [bh][d][t]
    short* yb  = Xb;                    // alias: attn output (B,T,C) bf16

    cvt_bf16<<<2048, 256, 0, stream>>>(x, Xb, 4194304);
    transpose_w<<<dim3(48, 16), 256, 0, stream>>>(W_attn, Wat, 3072, 1024);
    transpose_w<<<dim3(16, 16), 256, 0, stream>>>(W_proj, Wpt, 1024, 1024);
    qkv_gemm<<<dim3(32, 24), 256, 0, stream>>>(Xb, Wat, b_attn, qb, kb, vb);
    attn_kernel<<<dim3(32, 16), 256, 0, stream>>>(qb, kb, vb, yb);
    proj_gemm<<<dim3(32, 8), 256, 0, stream>>>(yb, Wpt, b_proj, out);
}

// Round 6
// 125.754 us; speedup vs baseline: 2.6993x; 1.0890x over previous
//
#include <hip/hip_runtime.h>

#define N_HEAD 16

typedef __attribute__((ext_vector_type(8))) __bf16 bf16x8;
typedef __attribute__((ext_vector_type(8))) short  s16x8;
typedef __attribute__((ext_vector_type(4))) short  s16x4;
typedef __attribute__((ext_vector_type(4))) float  f32x4;
typedef __attribute__((ext_vector_type(4))) unsigned u32x4;

#if __has_builtin(__builtin_amdgcn_exp2f)
#define EXP2(x) __builtin_amdgcn_exp2f(x)
#else
#define EXP2(x) exp2f(x)
#endif
#if __has_builtin(__builtin_amdgcn_rcpf)
#define RCP(x) __builtin_amdgcn_rcpf(x)
#else
#define RCP(x) (1.0f / (x))
#endif

static __device__ __forceinline__ short f2bf(float f) {
    unsigned u = __builtin_bit_cast(unsigned, f);
    unsigned r = (u + 0x7FFFu + ((u >> 16) & 1u)) >> 16;
    return (short)r;
}

static __device__ __forceinline__ unsigned cvt_pk_bf16(float lo, float hi) {
    unsigned d;
    asm("v_cvt_pk_bf16_f32 %0, %1, %2" : "=v"(d) : "v"(lo), "v"(hi));
    return d;
}

static __device__ __forceinline__ void gload_lds16(const void* g, void* l) {
    __builtin_amdgcn_global_load_lds(
        (const __attribute__((address_space(1))) void*)g,
        (__attribute__((address_space(3))) void*)l, 16, 0, 0);
}

// ------------------------------------------------------------ pre-pass: X -> bf16
__global__ __launch_bounds__(256) void cvt_bf16(
    const float* __restrict__ X, short* __restrict__ Y, int n)
{
    int idx = blockIdx.x * 256 + threadIdx.x;
    size_t base = (size_t)idx * 8;
    if (base + 8 > (size_t)n) return;
    float4 f0 = *(const float4*)&X[base];
    float4 f1 = *(const float4*)&X[base + 4];
    s16x8 o;
    o[0] = f2bf(f0.x); o[1] = f2bf(f0.y); o[2] = f2bf(f0.z); o[3] = f2bf(f0.w);
    o[4] = f2bf(f1.x); o[5] = f2bf(f1.y); o[6] = f2bf(f1.z); o[7] = f2bf(f1.w);
    *(s16x8*)&Y[base] = o;
}

// ------------------------------------------- pre-pass: W [K][N] fp32 -> Wt [N][K] bf16
__global__ __launch_bounds__(256) void transpose_w(
    const float* __restrict__ W, short* __restrict__ Wt, int N, int K)
{
    __shared__ short Ts[64][72];
    const int n0 = blockIdx.x * 64, k0 = blockIdx.y * 64;
    const int tid = threadIdx.x;
    const int r = tid >> 4, c4 = (tid & 15) * 4;
#pragma unroll
    for (int i = 0; i < 4; ++i) {
        int row = r + i * 16;
        float4 f = *(const float4*)&W[(size_t)(k0 + row) * N + n0 + c4];
        s16x4 s = { f2bf(f.x), f2bf(f.y), f2bf(f.z), f2bf(f.w) };
        *(s16x4*)&Ts[row][c4] = s;
    }
    __syncthreads();
#pragma unroll
    for (int i = 0; i < 4; ++i) {
        int row = r + i * 16;
        s16x4 s = { Ts[c4 + 0][row], Ts[c4 + 1][row], Ts[c4 + 2][row], Ts[c4 + 3][row] };
        *(s16x4*)&Wt[(size_t)(n0 + row) * K + k0 + c4] = s;
    }
}

// ---------------------------------------------------------------- GEMM 1: qkv
// q pre-scaled by 0.125*log2(e); V stored transposed [bh][d][t].
__global__ __launch_bounds__(256) void qkv_gemm(
    const short* __restrict__ Xb,
    const short* __restrict__ Wt,
    const float* __restrict__ bias,
    short* __restrict__ Qo, short* __restrict__ Ko, short* __restrict__ Vo)
{
    __shared__ short As[2][128 * 32];
    __shared__ short Bs[2][128 * 32];
    const int tid = threadIdx.x, wave = tid >> 6, lane = tid & 63;
    const int row0 = blockIdx.x * 128, col0 = blockIdx.y * 128;
    const int srow = wave * 16 + (lane >> 2);
    const int scol = (lane & 3) * 8;
    const short* aS = Xb + (size_t)(row0 + srow) * 1024 + scol;
    const short* bS = Wt + (size_t)(col0 + srow) * 1024 + scol;
    const int woff = wave * 512;
    const int wr = (wave >> 1) * 64, wc = (wave & 1) * 64;
    const int arow = lane & 15, ksub = (lane >> 4) * 8;

    f32x4 acc[4][4] = {};

    gload_lds16(aS,             As[0] + woff);
    gload_lds16(aS + 64 * 1024, As[0] + woff + 2048);
    gload_lds16(bS,             Bs[0] + woff);
    gload_lds16(bS + 64 * 1024, Bs[0] + woff + 2048);
    __syncthreads();

    int cur = 0;
    for (int k0 = 0; k0 < 1024; k0 += 32) {
        if (k0 + 32 < 1024) {
            gload_lds16(aS + k0 + 32,             As[cur ^ 1] + woff);
            gload_lds16(aS + k0 + 32 + 64 * 1024, As[cur ^ 1] + woff + 2048);
            gload_lds16(bS + k0 + 32,             Bs[cur ^ 1] + woff);
            gload_lds16(bS + k0 + 32 + 64 * 1024, Bs[cur ^ 1] + woff + 2048);
        }
        bf16x8 af[4], bfr[4];
#pragma unroll
        for (int i = 0; i < 4; ++i) af[i]  = *(const bf16x8*)&As[cur][(wr + i * 16 + arow) * 32 + ksub];
#pragma unroll
        for (int j = 0; j < 4; ++j) bfr[j] = *(const bf16x8*)&Bs[cur][(wc + j * 16 + arow) * 32 + ksub];
#pragma unroll
        for (int i = 0; i < 4; ++i)
#pragma unroll
            for (int j = 0; j < 4; ++j)
                acc[i][j] = __builtin_amdgcn_mfma_f32_16x16x32_bf16(af[i], bfr[j], acc[i][j], 0, 0, 0);
        __syncthreads();
        cur ^= 1;
    }

    const int ccol = lane & 15, crow = (lane >> 4) * 4;
#pragma unroll
    for (int i = 0; i < 4; ++i)
#pragma unroll
        for (int j = 0; j < 4; ++j)
#pragma unroll
            for (int r = 0; r < 4; ++r) {
                int m = row0 + wr + i * 16 + crow + r;
                int n = col0 + wc + j * 16 + ccol;
                float val = acc[i][j][r] + bias[n];
                int which = n >> 10;
                int nc = n & 1023;
                int head = nc >> 6, hd = nc & 63;
                int b = m >> 11, t = m & 2047;
                if (which == 0) {
                    Qo[((size_t)(b * N_HEAD + head) * 2048 + t) * 64 + hd] = f2bf(val * 0.18033688f);
                } else if (which == 1) {
                    Ko[((size_t)(b * N_HEAD + head) * 2048 + t) * 64 + hd] = f2bf(val);
                } else {
                    Vo[((size_t)(b * N_HEAD + head) * 64 + hd) * 2048 + t] = f2bf(val);
                }
            }
}

// ---------------------------------------------------------- flash attention v4b
// Swapped QK^T (S^T = mfma(K,Q)) with kappa-permuted K-row staging so each lane's
// S^T values are exactly its PV B-fragment -> P stays in registers (no LDS).
// kappa(rho) = (rho5<<5)|(rho23<<3)|(rho4<<2)|(rho01): rho-bit3 -> kappa-bit4,
// so the wave's 2nd staging call (LDS rows rho+8) reads global rows kappa+16.
__global__ __launch_bounds__(256) void attn_kernel(
    const short* __restrict__ Q, const short* __restrict__ K,
    const short* __restrict__ Vt, short* __restrict__ Y)
{
    __shared__ short Ks[2][64 * 64];
    __shared__ short Vs[2][64 * 64];
    const int bh = blockIdx.x;
    const int qt = gridDim.y - 1 - blockIdx.y;   // big tiles dispatched first
    const int q0 = qt * 128;
    const int b = bh >> 4, h = bh & 15;
    const short* Qh = Q  + (size_t)bh * 2048 * 64;
    const short* Kh = K  + (size_t)bh * 2048 * 64;
    const short* Vh = Vt + (size_t)bh * 64 * 2048;
    const int tid = threadIdx.x, wave = tid >> 6, lane = tid & 63;
    const int qrow0 = q0 + wave * 32;
    const int arow = lane & 15, g = lane >> 4;

    // staging: dest LDS row rho = wave*16 + (lane>>3) (+8 on 2nd call)
    const int rho = wave * 16 + (lane >> 3);
    const int kappa = ((rho >> 5) << 5) | (((rho >> 2) & 3) << 3)
                    | (((rho >> 4) & 1) << 2) | (rho & 3);
    const int xchunk = 8 * ((lane & 7) ^ (rho & 7));   // inverse XOR-swizzle on source
    const short* kSrc = Kh + (size_t)kappa * 64 + xchunk;
    const short* vSrc = Vh + (size_t)rho * 2048 + xchunk;

    bf16x8 qfr[2][2];
#pragma unroll
    for (int qf = 0; qf < 2; ++qf)
#pragma unroll
        for (int c = 0; c < 2; ++c)
            qfr[qf][c] = *(const bf16x8*)&Qh[(size_t)(qrow0 + qf * 16 + arow) * 64 + c * 32 + (g * 8)];

    f32x4 o[2][4] = {};          // O^T: col q=arow, row d=j*16+4g+r
    float lsum[2] = {};

    const int nt = (q0 + 128) >> 6;

    gload_lds16(kSrc,            Ks[0] + wave * 1024);
    gload_lds16(kSrc + 1024,     Ks[0] + wave * 1024 + 512);   // kappa(rho+8)=kappa+16
    gload_lds16(vSrc,            Vs[0] + wave * 1024);
    gload_lds16(vSrc + 8 * 2048, Vs[0] + wave * 1024 + 512);
    __syncthreads();

    int cur = 0;
    for (int t = 0; t < nt; ++t) {
        const int kt = t << 6;
        if (t + 1 < nt) {
            const int kn = kt + 64;
            short* kD = Ks[cur ^ 1] + wave * 1024;
            short* vD = Vs[cur ^ 1] + wave * 1024;
            gload_lds16(kSrc + (size_t)kn * 64,        kD);
            gload_lds16(kSrc + (size_t)kn * 64 + 1024, kD + 512);
            gload_lds16(vSrc + kn,                     vD);
            gload_lds16(vSrc + kn + 8 * 2048,          vD + 512);
        }
        if (kt <= qrow0 + 31) {
            const short* Kc = Ks[cur];
            const short* Vc = Vs[cur];
            const bool need_mask = (kt + 64) > qrow0;
            f32x4 s[2][4] = {};      // S^T [qf][kc]: key = kt + kappa(kc*16+4g+r)
#pragma unroll
            for (int kc = 0; kc < 4; ++kc) {
                int krow = kc * 16 + arow;
                int xr = krow & 7;
#pragma unroll
                for (int c = 0; c < 2; ++c) {
                    bf16x8 kf = *(const bf16x8*)&Kc[krow * 64 + (((c * 4 + g) ^ xr) * 8)];
#pragma unroll
                    for (int qf = 0; qf < 2; ++qf)
                        s[qf][kc] = __builtin_amdgcn_mfma_f32_16x16x32_bf16(kf, qfr[qf][c], s[qf][kc], 0, 0, 0);
                }
            }
            if (need_mask) {
#pragma unroll
                for (int qf = 0; qf < 2; ++qf) {
                    int q = qrow0 + qf * 16 + arow;
#pragma unroll
                    for (int kc = 0; kc < 4; ++kc) {
                        int keyb = kt + ((kc >> 1) << 5) + (g << 3) + ((kc & 1) << 2);
#pragma unroll
                        for (int r = 0; r < 4; ++r)
                            if (keyb + r > q) s[qf][kc][r] = -3.0e38f;
                    }
                }
            }
            // softmax (no max-sub) + in-register P pack: pa[qf][4c+t] = B-frag reg t
            unsigned pa[2][8];
#pragma unroll
            for (int qf = 0; qf < 2; ++qf) {
#pragma unroll
                for (int kc = 0; kc < 4; ++kc) {
                    float p0 = EXP2(s[qf][kc][0]);
                    float p1 = EXP2(s[qf][kc][1]);
                    float p2 = EXP2(s[qf][kc][2]);
                    float p3 = EXP2(s[qf][kc][3]);
                    lsum[qf] += (p0 + p1) + (p2 + p3);
                    pa[qf][kc * 2 + 0] = cvt_pk_bf16(p0, p1);
                    pa[qf][kc * 2 + 1] = cvt_pk_bf16(p2, p3);
                }
            }
            // PV: O^T += V^T-frag * P^T-frag
#pragma unroll
            for (int c = 0; c < 2; ++c) {
                bf16x8 pb0 = __builtin_bit_cast(bf16x8,
                    (u32x4){ pa[0][4 * c], pa[0][4 * c + 1], pa[0][4 * c + 2], pa[0][4 * c + 3] });
                bf16x8 pb1 = __builtin_bit_cast(bf16x8,
                    (u32x4){ pa[1][4 * c], pa[1][4 * c + 1], pa[1][4 * c + 2], pa[1][4 * c + 3] });
#pragma unroll
                for (int j = 0; j < 4; ++j) {
                    int d = j * 16 + arow;
                    bf16x8 vf = *(const bf16x8*)&Vc[d * 64 + (((c * 4 + g) ^ (d & 7)) * 8)];
                    o[0][j] = __builtin_amdgcn_mfma_f32_16x16x32_bf16(vf, pb0, o[0][j], 0, 0, 0);
                    o[1][j] = __builtin_amdgcn_mfma_f32_16x16x32_bf16(vf, pb1, o[1][j], 0, 0, 0);
                }
            }
        }
        __syncthreads();
        cur ^= 1;
    }

    // epilogue: l-reduce across the 4 lane-groups, normalize, 8B stores
#pragma unroll
    for (int qf = 0; qf < 2; ++qf) {
        float l = lsum[qf];
        l += __shfl_xor(l, 16);
        l += __shfl_xor(l, 32);
        float li = RCP(l);
        int t = qrow0 + qf * 16 + arow;
#pragma unroll
        for (int j = 0; j < 4; ++j) {
            s16x4 ov = { f2bf(o[qf][j][0] * li), f2bf(o[qf][j][1] * li),
                         f2bf(o[qf][j][2] * li), f2bf(o[qf][j][3] * li) };
            *(s16x4*)&Y[((size_t)(b * 2048 + t)) * 1024 + h * 64 + j * 16 + 4 * g] = ov;
        }
    }
}

// ---------------------------------------------------------------- GEMM 2: proj
__global__ __launch_bounds__(256) void proj_gemm(
    const short* __restrict__ Yb,
    const short* __restrict__ Wpt,
    const float* __restrict__ bias,
    float* __restrict__ Out)
{
    __shared__ short As[2][128 * 32];
    __shared__ short Bs[2][128 * 32];
    const int tid = threadIdx.x, wave = tid >> 6, lane = tid & 63;
    const int row0 = blockIdx.x * 128, col0 = blockIdx.y * 128;
    const int srow = wave * 16 + (lane >> 2);
    const int scol = (lane & 3) * 8;
    const short* aS = Yb  + (size_t)(row0 + srow) * 1024 + scol;
    const short* bS = Wpt + (size_t)(col0 + srow) * 1024 + scol;
    const int woff = wave * 512;
    const int wr = (wave >> 1) * 64, wc = (wave & 1) * 64;
    const int arow = lane & 15, ksub = (lane >> 4) * 8;

    f32x4 acc[4][4] = {};

    gload_lds16(aS,             As[0] + woff);
    gload_lds16(aS + 64 * 1024, As[0] + woff + 2048);
    gload_lds16(bS,             Bs[0] + woff);
    gload_lds16(bS + 64 * 1024, Bs[0] + woff + 2048);
    __syncthreads();

    int cur = 0;
    for (int k0 = 0; k0 < 1024; k0 += 32) {
        if (k0 + 32 < 1024) {
            gload_lds16(aS + k0 + 32,             As[cur ^ 1] + woff);
            gload_lds16(aS + k0 + 32 + 64 * 1024, As[cur ^ 1] + woff + 2048);
            gload_lds16(bS + k0 + 32,             Bs[cur ^ 1] + woff);
            gload_lds16(bS + k0 + 32 + 64 * 1024, Bs[cur ^ 1] + woff + 2048);
        }
        bf16x8 af[4], bfr[4];
#pragma unroll
        for (int i = 0; i < 4; ++i) af[i]  = *(const bf16x8*)&As[cur][(wr + i * 16 + arow) * 32 + ksub];
#pragma unroll
        for (int j = 0; j < 4; ++j) bfr[j] = *(const bf16x8*)&Bs[cur][(wc + j * 16 + arow) * 32 + ksub];
#pragma unroll
        for (int i = 0; i < 4; ++i)
#pragma unroll
            for (int j = 0; j < 4; ++j)
                acc[i][j] = __builtin_amdgcn_mfma_f32_16x16x32_bf16(af[i], bfr[j], acc[i][j], 0, 0, 0);
        __syncthreads();
        cur ^= 1;
    }

    const int ccol = lane & 15, crow = (lane >> 4) * 4;
#pragma unroll
    for (int i = 0; i < 4; ++i)
#pragma unroll
        for (int j = 0; j < 4; ++j)
#pragma unroll
            for (int r = 0; r < 4; ++r) {
                int m = row0 + wr + i * 16 + crow + r;
                int n = col0 + wc + j * 16 + ccol;
                Out[(size_t)m * 1024 + n] = acc[i][j][r] + bias[n];
            }
}

// ------------------------------------------------------------------- launch
extern "C" void kernel_launch(void* const* d_in, const int* in_sizes, int n_in,
                              void* d_out, int out_size, void* d_ws, size_t ws_size,
                              hipStream_t stream) {
    const float* x      = (const float*)d_in[0];
    const float* W_attn = (const float*)d_in[1];
    const float* b_attn = (const float*)d_in[2];
    const float* W_proj = (const float*)d_in[3];
    const float* b_proj = (const float*)d_in[4];
    float* out = (float*)d_out;

    short* Xb  = (short*)d_ws;          // dead after qkv -> aliased by yb
    short* Wat = Xb + 4194304;          // 3072x1024
    short* Wpt = Wat + 3145728;         // 1024x1024
    short* qb  = Wpt + 1048576;
    short* kb  = qb + 4194304;
    short* vb  = kb + 4194304;          // V^T: [bh][d][t]
    short* yb  = Xb;                    // attn output (B,T,C) bf16

    cvt_bf16<<<2048, 256, 0, stream>>>(x, Xb, 4194304);
    transpose_w<<<dim3(48, 16), 256, 0, stream>>>(W_attn, Wat, 3072, 1024);
    transpose_w<<<dim3(16, 16), 256, 0, stream>>>(W_proj, Wpt, 1024, 1024);
    qkv_gemm<<<dim3(32, 24), 256, 0, stream>>>(Xb, Wat, b_attn, qb, kb, vb);
    attn_kernel<<<dim3(32, 16), 256, 0, stream>>>(qb, kb, vb, yb);
    proj_gemm<<<dim3(32, 8), 256, 0, stream>>>(yb, Wpt, b_proj, out);
}

// Round 7
// 114.960 us; speedup vs baseline: 2.9527x; 1.0939x over previous
//
#include <hip/hip_runtime.h>

#define N_HEAD 16

typedef __attribute__((ext_vector_type(8))) __bf16 bf16x8;
typedef __attribute__((ext_vector_type(8))) short  s16x8;
typedef __attribute__((ext_vector_type(4))) short  s16x4;
typedef __attribute__((ext_vector_type(4))) float  f32x4;
typedef __attribute__((ext_vector_type(4))) unsigned u32x4;

#if __has_builtin(__builtin_amdgcn_exp2f)
#define EXP2(x) __builtin_amdgcn_exp2f(x)
#else
#define EXP2(x) exp2f(x)
#endif
#if __has_builtin(__builtin_amdgcn_rcpf)
#define RCP(x) __builtin_amdgcn_rcpf(x)
#else
#define RCP(x) (1.0f / (x))
#endif

static __device__ __forceinline__ short f2bf(float f) {
    unsigned u = __builtin_bit_cast(unsigned, f);
    unsigned r = (u + 0x7FFFu + ((u >> 16) & 1u)) >> 16;
    return (short)r;
}

static __device__ __forceinline__ unsigned cvt_pk_bf16(float lo, float hi) {
    unsigned d;
    asm("v_cvt_pk_bf16_f32 %0, %1, %2" : "=v"(d) : "v"(lo), "v"(hi));
    return d;
}

static __device__ __forceinline__ void gload_lds16(const void* g, void* l) {
    __builtin_amdgcn_global_load_lds(
        (const __attribute__((address_space(1))) void*)g,
        (__attribute__((address_space(3))) void*)l, 16, 0, 0);
}

// ------------------------------------------------------------ pre-pass: X -> bf16
__global__ __launch_bounds__(256) void cvt_bf16(
    const float* __restrict__ X, short* __restrict__ Y, int n)
{
    int idx = blockIdx.x * 256 + threadIdx.x;
    size_t base = (size_t)idx * 8;
    if (base + 8 > (size_t)n) return;
    float4 f0 = *(const float4*)&X[base];
    float4 f1 = *(const float4*)&X[base + 4];
    s16x8 o;
    o[0] = f2bf(f0.x); o[1] = f2bf(f0.y); o[2] = f2bf(f0.z); o[3] = f2bf(f0.w);
    o[4] = f2bf(f1.x); o[5] = f2bf(f1.y); o[6] = f2bf(f1.z); o[7] = f2bf(f1.w);
    *(s16x8*)&Y[base] = o;
}

// ------------------------------------------- pre-pass: W [K][N] fp32 -> Wt [N][K] bf16
__global__ __launch_bounds__(256) void transpose_w(
    const float* __restrict__ W, short* __restrict__ Wt, int N, int K)
{
    __shared__ short Ts[64][72];
    const int n0 = blockIdx.x * 64, k0 = blockIdx.y * 64;
    const int tid = threadIdx.x;
    const int r = tid >> 4, c4 = (tid & 15) * 4;
#pragma unroll
    for (int i = 0; i < 4; ++i) {
        int row = r + i * 16;
        float4 f = *(const float4*)&W[(size_t)(k0 + row) * N + n0 + c4];
        s16x4 s = { f2bf(f.x), f2bf(f.y), f2bf(f.z), f2bf(f.w) };
        *(s16x4*)&Ts[row][c4] = s;
    }
    __syncthreads();
#pragma unroll
    for (int i = 0; i < 4; ++i) {
        int row = r + i * 16;
        s16x4 s = { Ts[c4 + 0][row], Ts[c4 + 1][row], Ts[c4 + 2][row], Ts[c4 + 3][row] };
        *(s16x4*)&Wt[(size_t)(n0 + row) * K + k0 + c4] = s;
    }
}

// ---------------------------------------------------------------- GEMM 1: qkv
// q pre-scaled by 0.125*log2(e); V stored transposed [bh][d][t].
__global__ __launch_bounds__(256) void qkv_gemm(
    const short* __restrict__ Xb,
    const short* __restrict__ Wt,
    const float* __restrict__ bias,
    short* __restrict__ Qo, short* __restrict__ Ko, short* __restrict__ Vo)
{
    __shared__ short As[2][128 * 32];
    __shared__ short Bs[2][128 * 32];
    const int tid = threadIdx.x, wave = tid >> 6, lane = tid & 63;
    const int row0 = blockIdx.x * 128, col0 = blockIdx.y * 128;
    const int srow = wave * 16 + (lane >> 2);
    const int scol = (lane & 3) * 8;
    const short* aS = Xb + (size_t)(row0 + srow) * 1024 + scol;
    const short* bS = Wt + (size_t)(col0 + srow) * 1024 + scol;
    const int woff = wave * 512;
    const int wr = (wave >> 1) * 64, wc = (wave & 1) * 64;
    const int arow = lane & 15, ksub = (lane >> 4) * 8;

    f32x4 acc[4][4] = {};

    gload_lds16(aS,             As[0] + woff);
    gload_lds16(aS + 64 * 1024, As[0] + woff + 2048);
    gload_lds16(bS,             Bs[0] + woff);
    gload_lds16(bS + 64 * 1024, Bs[0] + woff + 2048);
    __syncthreads();

    int cur = 0;
    for (int k0 = 0; k0 < 1024; k0 += 32) {
        if (k0 + 32 < 1024) {
            gload_lds16(aS + k0 + 32,             As[cur ^ 1] + woff);
            gload_lds16(aS + k0 + 32 + 64 * 1024, As[cur ^ 1] + woff + 2048);
            gload_lds16(bS + k0 + 32,             Bs[cur ^ 1] + woff);
            gload_lds16(bS + k0 + 32 + 64 * 1024, Bs[cur ^ 1] + woff + 2048);
        }
        bf16x8 af[4], bfr[4];
#pragma unroll
        for (int i = 0; i < 4; ++i) af[i]  = *(const bf16x8*)&As[cur][(wr + i * 16 + arow) * 32 + ksub];
#pragma unroll
        for (int j = 0; j < 4; ++j) bfr[j] = *(const bf16x8*)&Bs[cur][(wc + j * 16 + arow) * 32 + ksub];
#pragma unroll
        for (int i = 0; i < 4; ++i)
#pragma unroll
            for (int j = 0; j < 4; ++j)
                acc[i][j] = __builtin_amdgcn_mfma_f32_16x16x32_bf16(af[i], bfr[j], acc[i][j], 0, 0, 0);
        __syncthreads();
        cur ^= 1;
    }

    const int ccol = lane & 15, crow = (lane >> 4) * 4;
#pragma unroll
    for (int i = 0; i < 4; ++i)
#pragma unroll
        for (int j = 0; j < 4; ++j)
#pragma unroll
            for (int r = 0; r < 4; ++r) {
                int m = row0 + wr + i * 16 + crow + r;
                int n = col0 + wc + j * 16 + ccol;
                float val = acc[i][j][r] + bias[n];
                int which = n >> 10;
                int nc = n & 1023;
                int head = nc >> 6, hd = nc & 63;
                int b = m >> 11, t = m & 2047;
                if (which == 0) {
                    Qo[((size_t)(b * N_HEAD + head) * 2048 + t) * 64 + hd] = f2bf(val * 0.18033688f);
                } else if (which == 1) {
                    Ko[((size_t)(b * N_HEAD + head) * 2048 + t) * 64 + hd] = f2bf(val);
                } else {
                    Vo[((size_t)(b * N_HEAD + head) * 64 + hd) * 2048 + t] = f2bf(val);
                }
            }
}

// ---------------------------------------------------------- flash attention v5
// 64-row q-tiles (4 waves x 16 q-rows) -> 1024 blocks (4/CU) for latency hiding.
// Swapped QK^T with kappa-permuted K staging keeps P in registers (no LDS).
__global__ __launch_bounds__(256) void attn_kernel(
    const short* __restrict__ Q, const short* __restrict__ K,
    const short* __restrict__ Vt, short* __restrict__ Y)
{
    __shared__ short Ks[2][64 * 64];
    __shared__ short Vs[2][64 * 64];
    const int bh = blockIdx.x;
    const int qt = gridDim.y - 1 - blockIdx.y;   // big tiles dispatched first
    const int q0 = qt * 64;
    const int b = bh >> 4, h = bh & 15;
    const short* Qh = Q  + (size_t)bh * 2048 * 64;
    const short* Kh = K  + (size_t)bh * 2048 * 64;
    const short* Vh = Vt + (size_t)bh * 64 * 2048;
    const int tid = threadIdx.x, wave = tid >> 6, lane = tid & 63;
    const int qrow0 = q0 + wave * 16;
    const int arow = lane & 15, g = lane >> 4;

    // staging: dest LDS row rho = wave*16 + (lane>>3) (+8 on 2nd call)
    const int rho = wave * 16 + (lane >> 3);
    const int kappa = ((rho >> 5) << 5) | (((rho >> 2) & 3) << 3)
                    | (((rho >> 4) & 1) << 2) | (rho & 3);
    const int xchunk = 8 * ((lane & 7) ^ (rho & 7));   // inverse XOR-swizzle on source
    const short* kSrc = Kh + (size_t)kappa * 64 + xchunk;
    const short* vSrc = Vh + (size_t)rho * 2048 + xchunk;

    bf16x8 qfr[2];
#pragma unroll
    for (int c = 0; c < 2; ++c)
        qfr[c] = *(const bf16x8*)&Qh[(size_t)(qrow0 + arow) * 64 + c * 32 + (g * 8)];

    f32x4 o[4] = {};             // O^T: col q=arow, row d=j*16+4g+r
    float lsum = 0.f;

    const int nt = qt + 1;

    gload_lds16(kSrc,            Ks[0] + wave * 1024);
    gload_lds16(kSrc + 1024,     Ks[0] + wave * 1024 + 512);   // kappa(rho+8)=kappa+16
    gload_lds16(vSrc,            Vs[0] + wave * 1024);
    gload_lds16(vSrc + 8 * 2048, Vs[0] + wave * 1024 + 512);
    __syncthreads();

    int cur = 0;
    for (int t = 0; t < nt; ++t) {
        const int kt = t << 6;
        if (t + 1 < nt) {
            const int kn = kt + 64;
            short* kD = Ks[cur ^ 1] + wave * 1024;
            short* vD = Vs[cur ^ 1] + wave * 1024;
            gload_lds16(kSrc + (size_t)kn * 64,        kD);
            gload_lds16(kSrc + (size_t)kn * 64 + 1024, kD + 512);
            gload_lds16(vSrc + kn,                     vD);
            gload_lds16(vSrc + kn + 8 * 2048,          vD + 512);
        }
        if (kt <= qrow0 + 15) {          // wave-uniform skip of fully-masked tiles
            const short* Kc = Ks[cur];
            const short* Vc = Vs[cur];
            const bool need_mask = (kt + 64) > qrow0;
            f32x4 s[4] = {};             // S^T [kc]: key = kt + kappa(kc*16+4g+r)
#pragma unroll
            for (int kc = 0; kc < 4; ++kc) {
                int krow = kc * 16 + arow;
                int xr = krow & 7;
#pragma unroll
                for (int c = 0; c < 2; ++c) {
                    bf16x8 kf = *(const bf16x8*)&Kc[krow * 64 + (((c * 4 + g) ^ xr) * 8)];
                    s[kc] = __builtin_amdgcn_mfma_f32_16x16x32_bf16(kf, qfr[c], s[kc], 0, 0, 0);
                }
            }
            if (need_mask) {
                int q = qrow0 + arow;
#pragma unroll
                for (int kc = 0; kc < 4; ++kc) {
                    int keyb = kt + ((kc >> 1) << 5) + (g << 3) + ((kc & 1) << 2);
#pragma unroll
                    for (int r = 0; r < 4; ++r)
                        if (keyb + r > q) s[kc][r] = -3.0e38f;
                }
            }
            // softmax (no max-sub) + in-register P pack
            unsigned pa[8];
#pragma unroll
            for (int kc = 0; kc < 4; ++kc) {
                float p0 = EXP2(s[kc][0]);
                float p1 = EXP2(s[kc][1]);
                float p2 = EXP2(s[kc][2]);
                float p3 = EXP2(s[kc][3]);
                lsum += (p0 + p1) + (p2 + p3);
                pa[kc * 2 + 0] = cvt_pk_bf16(p0, p1);
                pa[kc * 2 + 1] = cvt_pk_bf16(p2, p3);
            }
            // PV: O^T += V^T-frag * P^T-frag
#pragma unroll
            for (int c = 0; c < 2; ++c) {
                bf16x8 pb = __builtin_bit_cast(bf16x8,
                    (u32x4){ pa[4 * c], pa[4 * c + 1], pa[4 * c + 2], pa[4 * c + 3] });
#pragma unroll
                for (int j = 0; j < 4; ++j) {
                    int d = j * 16 + arow;
                    bf16x8 vf = *(const bf16x8*)&Vc[d * 64 + (((c * 4 + g) ^ (d & 7)) * 8)];
                    o[j] = __builtin_amdgcn_mfma_f32_16x16x32_bf16(vf, pb, o[j], 0, 0, 0);
                }
            }
        }
        __syncthreads();
        cur ^= 1;
    }

    // epilogue: l-reduce across the 4 lane-groups, normalize, 8B stores
    {
        float l = lsum;
        l += __shfl_xor(l, 16);
        l += __shfl_xor(l, 32);
        float li = RCP(l);
        int t = qrow0 + arow;
#pragma unroll
        for (int j = 0; j < 4; ++j) {
            s16x4 ov = { f2bf(o[j][0] * li), f2bf(o[j][1] * li),
                         f2bf(o[j][2] * li), f2bf(o[j][3] * li) };
            *(s16x4*)&Y[((size_t)(b * 2048 + t)) * 1024 + h * 64 + j * 16 + 4 * g] = ov;
        }
    }
}

// ---------------------------------------------------------------- GEMM 2: proj
__global__ __launch_bounds__(256) void proj_gemm(
    const short* __restrict__ Yb,
    const short* __restrict__ Wpt,
    const float* __restrict__ bias,
    float* __restrict__ Out)
{
    __shared__ short As[2][128 * 32];
    __shared__ short Bs[2][128 * 32];
    const int tid = threadIdx.x, wave = tid >> 6, lane = tid & 63;
    const int row0 = blockIdx.x * 128, col0 = blockIdx.y * 128;
    const int srow = wave * 16 + (lane >> 2);
    const int scol = (lane & 3) * 8;
    const short* aS = Yb  + (size_t)(row0 + srow) * 1024 + scol;
    const short* bS = Wpt + (size_t)(col0 + srow) * 1024 + scol;
    const int woff = wave * 512;
    const int wr = (wave >> 1) * 64, wc = (wave & 1) * 64;
    const int arow = lane & 15, ksub = (lane >> 4) * 8;

    f32x4 acc[4][4] = {};

    gload_lds16(aS,             As[0] + woff);
    gload_lds16(aS + 64 * 1024, As[0] + woff + 2048);
    gload_lds16(bS,             Bs[0] + woff);
    gload_lds16(bS + 64 * 1024, Bs[0] + woff + 2048);
    __syncthreads();

    int cur = 0;
    for (int k0 = 0; k0 < 1024; k0 += 32) {
        if (k0 + 32 < 1024) {
            gload_lds16(aS + k0 + 32,             As[cur ^ 1] + woff);
            gload_lds16(aS + k0 + 32 + 64 * 1024, As[cur ^ 1] + woff + 2048);
            gload_lds16(bS + k0 + 32,             Bs[cur ^ 1] + woff);
            gload_lds16(bS + k0 + 32 + 64 * 1024, Bs[cur ^ 1] + woff + 2048);
        }
        bf16x8 af[4], bfr[4];
#pragma unroll
        for (int i = 0; i < 4; ++i) af[i]  = *(const bf16x8*)&As[cur][(wr + i * 16 + arow) * 32 + ksub];
#pragma unroll
        for (int j = 0; j < 4; ++j) bfr[j] = *(const bf16x8*)&Bs[cur][(wc + j * 16 + arow) * 32 + ksub];
#pragma unroll
        for (int i = 0; i < 4; ++i)
#pragma unroll
            for (int j = 0; j < 4; ++j)
                acc[i][j] = __builtin_amdgcn_mfma_f32_16x16x32_bf16(af[i], bfr[j], acc[i][j], 0, 0, 0);
        __syncthreads();
        cur ^= 1;
    }

    const int ccol = lane & 15, crow = (lane >> 4) * 4;
#pragma unroll
    for (int i = 0; i < 4; ++i)
#pragma unroll
        for (int j = 0; j < 4; ++j)
#pragma unroll
            for (int r = 0; r < 4; ++r) {
                int m = row0 + wr + i * 16 + crow + r;
                int n = col0 + wc + j * 16 + ccol;
                Out[(size_t)m * 1024 + n] = acc[i][j][r] + bias[n];
            }
}

// ------------------------------------------------------------------- launch
extern "C" void kernel_launch(void* const* d_in, const int* in_sizes, int n_in,
                              void* d_out, int out_size, void* d_ws, size_t ws_size,
                              hipStream_t stream) {
    const float* x      = (const float*)d_in[0];
    const float* W_attn = (const float*)d_in[1];
    const float* b_attn = (const float*)d_in[2];
    const float* W_proj = (const float*)d_in[3];
    const float* b_proj = (const float*)d_in[4];
    float* out = (float*)d_out;

    short* Xb  = (short*)d_ws;          // dead after qkv -> aliased by yb
    short* Wat = Xb + 4194304;          // 3072x1024
    short* Wpt = Wat + 3145728;         // 1024x1024
    short* qb  = Wpt + 1048576;
    short* kb  = qb + 4194304;
    short* vb  = kb + 4194304;          // V^T: [bh][d][t]
    short* yb  = Xb;                    // attn output (B,T,C) bf16

    cvt_bf16<<<2048, 256, 0, stream>>>(x, Xb, 4194304);
    transpose_w<<<dim3(48, 16), 256, 0, stream>>>(W_attn, Wat, 3072, 1024);
    transpose_w<<<dim3(16, 16), 256, 0, stream>>>(W_proj, Wpt, 1024, 1024);
    qkv_gemm<<<dim3(32, 24), 256, 0, stream>>>(Xb, Wat, b_attn, qb, kb, vb);
    attn_kernel<<<dim3(32, 32), 256, 0, stream>>>(qb, kb, vb, yb);
    proj_gemm<<<dim3(32, 8), 256, 0, stream>>>(yb, Wpt, b_proj, out);
}